// Round 4
// baseline (819.331 us; speedup 1.0000x reference)
//
#include <hip/hip_runtime.h>

typedef short short8 __attribute__((ext_vector_type(8)));
typedef float f32x4 __attribute__((ext_vector_type(4)));

#define T_ 12
#define B_ 256
#define N_ 35
#define M_ 29
#define H_ 64
#define R_ 7

// ---- ws (shorts) layout: packed bf16 MFMA B-fragments ----
// W6F   @0     : 6 mats x [nt4][ks2][64 lanes][8]  = 24576 shorts
// WQKF  @24576 : 2 mats x [nt4][64][8]             = 4096
// WRELF @28672 : 7 r    x [nt4][64][8]             = 14336
// total 43008 shorts = 86016 B

// ---- msg_kernel LDS (bytes), all regions 128-aligned where XOR-swizzled ----
#define XFRAG_OFF 0        // 3 mt x [64][16B] bf16 A-frags of x      (3072)
#define Q_OFF     3072     // fp32 [35][64] swz                        (9216, 36 rows)
#define K_OFF     12288    // fp32 [35][64] linear                     (8960)
#define S_OFF     21248    // fp32 [35][36] softmax sum                (5040)
#define AN_OFF    26288    // bf16 [3][35][36]                         (7560)
#define AR_OFF    33920    // bf16 [48][64] swz                        (6144)
#define XW_OFF    40064    // bf16 [64 col][64 k] swz                  (8192)
#define SMEM_A    48256

__device__ __forceinline__ unsigned short f2bf(float f) {
    unsigned int u = __float_as_uint(f);
    u += 0x7fffu + ((u >> 16) & 1u);
    return (unsigned short)(u >> 16);
}
__device__ __forceinline__ float bf2f(unsigned short s) {
    return __uint_as_float(((unsigned int)s) << 16);
}

// ---------------- pack: weights -> bf16 fragment order in ws ----------------
__global__ void pack_kernel(const float* __restrict__ Wq, const float* __restrict__ Wk,
                            const float* __restrict__ coef, const float* __restrict__ V,
                            const float* __restrict__ Uz, const float* __restrict__ Wz,
                            const float* __restrict__ Ur, const float* __restrict__ Wrg,
                            const float* __restrict__ Uh, const float* __restrict__ Wh,
                            unsigned short* __restrict__ ws) {
    int idx = blockIdx.x * 256 + threadIdx.x;   // grid covers exactly 43008
    if (idx < 24576) {                          // W6: mat*4096 + nt*1024 + ks*512 + l*8 + i
        int mat = idx >> 12, rem = idx & 4095;
        int i = rem & 7, l = (rem >> 3) & 63, ks = (rem >> 9) & 1, nt = rem >> 10;
        int j = ks * 32 + ((l >> 4) << 3) + i, c = nt * 16 + (l & 15);
        const float* W = (mat == 0) ? Uz : (mat == 1) ? Wz : (mat == 2) ? Ur
                       : (mat == 3) ? Wrg : (mat == 4) ? Uh : Wh;
        ws[idx] = f2bf(W[j * 64 + c]);
    } else if (idx < 28672) {                   // WQK: 24576 + mq*2048 + nt*512 + l*8 + i
        int rem = idx - 24576;
        int mq = rem >> 11; rem &= 2047;
        int i = rem & 7, l = (rem >> 3) & 63, nt = rem >> 9;
        int j = ((l >> 4) << 3) + i, c = nt * 16 + (l & 15);
        const float* W = mq ? Wk : Wq;
        ws[idx] = (j < M_) ? f2bf(W[j * 64 + c]) : (unsigned short)0;
    } else {                                    // WREL: 28672 + r*2048 + nt*512 + l*8 + i
        int rem = idx - 28672;
        int r = rem >> 11; rem &= 2047;
        int i = rem & 7, l = (rem >> 3) & 63, nt = rem >> 9;
        int j = ((l >> 4) << 3) + i, c = nt * 16 + (l & 15);
        unsigned short v = 0;
        if (j < M_) {
            float a = 0.f;
#pragma unroll
            for (int bb = 0; bb < 3; ++bb) a += coef[r * 3 + bb] * V[(bb * M_ + j) * 64 + c];
            v = f2bf(a);
        }
        ws[idx] = v;
    }
}

// ---------------- msg: one block per (t,b); msg fp32 -> out[t] ----------------
__launch_bounds__(512, 4)
__global__ void msg_kernel(const float* __restrict__ x,
                           const float* __restrict__ As, const float* __restrict__ Af,
                           const float* __restrict__ At,
                           const unsigned short* __restrict__ wsF,
                           float* __restrict__ out) {
    __shared__ __align__(16) char smem[SMEM_A];
    const int blk = blockIdx.x;
    const int t = blk >> 8, b = blk & 255;
    const int tid = threadIdx.x, wv = tid >> 6, ln = tid & 63;
    const unsigned short* WQKF  = wsF + 24576;
    const unsigned short* WRELF = wsF + 28672;
    const float* __restrict__ xt = x + ((size_t)t * B_ + b) * (N_ * M_);

    // init: pack x A-frags, zero S, zero AR/XW pads
    for (int e = tid; e < 1536; e += 512) {
        int mt = e >> 9, l = (e >> 3) & 63, i = e & 7;
        int row = mt * 16 + (l & 15), k = ((l >> 4) << 3) + i;
        float v = (row < N_ && k < M_) ? xt[row * M_ + k] : 0.f;
        *(unsigned short*)(smem + XFRAG_OFF + e * 2) = f2bf(v);
    }
    for (int e = tid; e < 35 * 36; e += 512) *(float*)(smem + S_OFF + e * 4) = 0.f;
    for (int e = tid; e < 3072; e += 512) {
        int row = e >> 6, kk = e & 63;
        if (row >= N_ || kk >= N_) {
            int a = AR_OFF + row * 128 + kk * 2; a ^= (row & 7) << 4;
            *(unsigned short*)(smem + a) = 0;
        }
    }
    for (int e = tid; e < 4096; e += 512) {
        int col = e >> 6, kk = e & 63;
        if (kk >= N_) {
            int a = XW_OFF + col * 128 + kk * 2; a ^= (col & 7) << 4;
            *(unsigned short*)(smem + a) = 0;
        }
    }
    __syncthreads();

    // p2: q = x@Wq (swz fp32), k = x@Wk (linear fp32)
    for (int tile = wv; tile < 24; tile += 8) {
        int qk = (tile >= 12) ? 1 : 0;
        int tt = tile - 12 * qk;
        int mt = tt >> 2, nt = tt & 3;
        short8 a  = *(const short8*)(smem + XFRAG_OFF + (mt * 64 + ln) * 16);
        short8 bb = *(const short8*)(WQKF + (qk * 4 + nt) * 512 + ln * 8);
        f32x4 d = {0.f, 0.f, 0.f, 0.f};
        d = __builtin_amdgcn_mfma_f32_16x16x32_bf16(a, bb, d, 0, 0, 0);
        int col = nt * 16 + (ln & 15);
#pragma unroll
        for (int j = 0; j < 4; ++j) {
            int row = mt * 16 + ((ln >> 4) << 2) + j;
            if (row < N_) {
                if (qk) *(float*)(smem + K_OFF + (row * 64 + col) * 4) = d[j];
                else {
                    int ad = (Q_OFF + row * 256 + col * 4) ^ ((row & 7) << 4);
                    *(float*)(smem + ad) = d[j];
                }
            }
        }
    }
    __syncthreads();

    // p3: wave = head; lane = n-row; broadcast K reads; atomicAdd softmax into S
    {
        const int hd = wv, n = ln, nn = (n < N_) ? n : 34;
        const int qb = Q_OFF + nn * 256 + hd * 32;
        const int swzq = (nn & 7) << 4;
        f32x4 q0 = *(const f32x4*)(smem + (qb ^ swzq));
        f32x4 q1 = *(const f32x4*)(smem + ((qb + 16) ^ swzq));
        float s[35];
#pragma unroll
        for (int m = 0; m < N_; ++m) {
            f32x4 k0 = *(const f32x4*)(smem + K_OFF + (m * 64 + hd * 8) * 4);
            f32x4 k1 = *(const f32x4*)(smem + K_OFF + (m * 64 + hd * 8 + 4) * 4);
            float acc = q0[0]*k0[0] + q0[1]*k0[1] + q0[2]*k0[2] + q0[3]*k0[3]
                      + q1[0]*k1[0] + q1[1]*k1[1] + q1[2]*k1[2] + q1[3]*k1[3];
            s[m] = acc * 0.3535533905932738f;
        }
        float mx = s[0];
#pragma unroll
        for (int m = 1; m < N_; ++m) mx = fmaxf(mx, s[m]);
        float sum = 0.f;
#pragma unroll
        for (int m = 0; m < N_; ++m) { s[m] = __expf(s[m] - mx); sum += s[m]; }
        float inv = 1.f / sum;
        if (n < N_) {
            float* Sp = (float*)(smem + S_OFF) + n * 36;
#pragma unroll
            for (int m = 0; m < N_; ++m) atomicAdd(Sp + m, s[m] * inv);
        }
    }
    __syncthreads();

    // p4: An = l2norm(A * S) along n (4 lanes per (mat,col))
    if (tid < 420) {
        int g = tid >> 2, sub = tid & 3;
        int mat = g / N_, j = g - N_ * mat;
        const float* __restrict__ A = (mat == 0) ? As : ((mat == 1) ? Af : At);
        float vals[9]; float ss = 0.f;
#pragma unroll
        for (int i = 0; i < 9; ++i) {
            int n = sub + 4 * i;
            float vv = 0.f;
            if (n < N_) vv = A[n * N_ + j] * *((const float*)(smem + S_OFF) + n * 36 + j);
            vals[i] = vv; ss += vv * vv;
        }
        ss += __shfl_xor(ss, 1);
        ss += __shfl_xor(ss, 2);
        float inv = 1.f / fmaxf(sqrtf(ss), 1e-12f);
#pragma unroll
        for (int i = 0; i < 9; ++i) {
            int n = sub + 4 * i;
            if (n < N_)
                *(unsigned short*)(smem + AN_OFF + (mat * 1260 + n * 36 + j) * 2) = f2bf(vals[i] * inv);
        }
    }
    __syncthreads();

    // p5: per relation: xw = x@Wrel_r, A_r combo, msg = relu(A_r@xw) -> out[t]
    for (int r = 0; r < R_; ++r) {
        float c0, c1, c2;
        switch (r) {
            case 0: c0 = 1.f;  c1 = 0.f;  c2 = 0.f;  break;
            case 1: c0 = 0.f;  c1 = 1.f;  c2 = 0.f;  break;
            case 2: c0 = 0.f;  c1 = 0.f;  c2 = 1.f;  break;
            case 3: c0 = .5f;  c1 = .5f;  c2 = 0.f;  break;
            case 4: c0 = .5f;  c1 = 0.f;  c2 = .5f;  break;
            case 5: c0 = 0.f;  c1 = .5f;  c2 = .5f;  break;
            default: c0 = c1 = c2 = (1.f / 3.f);     break;
        }
        for (int tile = wv; tile < 12; tile += 8) {
            int mt = tile >> 2, nt = tile & 3;
            short8 a  = *(const short8*)(smem + XFRAG_OFF + (mt * 64 + ln) * 16);
            short8 bb = *(const short8*)(WRELF + (r * 4 + nt) * 512 + ln * 8);
            f32x4 d = {0.f, 0.f, 0.f, 0.f};
            d = __builtin_amdgcn_mfma_f32_16x16x32_bf16(a, bb, d, 0, 0, 0);
            int col = nt * 16 + (ln & 15);
#pragma unroll
            for (int j = 0; j < 4; ++j) {
                int krow = mt * 16 + ((ln >> 4) << 2) + j;
                if (krow < N_) {
                    int ad = (XW_OFF + col * 128 + krow * 2) ^ ((col & 7) << 4);
                    *(unsigned short*)(smem + ad) = f2bf(d[j]);
                }
            }
        }
        for (int e = tid; e < 1225; e += 512) {
            int n = e / 35, kk = e % 35;
            float v = c0 * bf2f(*(const unsigned short*)(smem + AN_OFF + (n * 36 + kk) * 2))
                    + c1 * bf2f(*(const unsigned short*)(smem + AN_OFF + (1260 + n * 36 + kk) * 2))
                    + c2 * bf2f(*(const unsigned short*)(smem + AN_OFF + (2520 + n * 36 + kk) * 2));
            int ad = (AR_OFF + n * 128 + kk * 2) ^ ((n & 7) << 4);
            *(unsigned short*)(smem + ad) = f2bf(v);
        }
        __syncthreads();
        float* __restrict__ outr = out + (((size_t)t * R_ + r) * B_ + b) * (N_ * 64);
        for (int tile = wv; tile < 12; tile += 8) {
            int mt = tile >> 2, nt = tile & 3;
            f32x4 d = {0.f, 0.f, 0.f, 0.f};
#pragma unroll
            for (int ks = 0; ks < 2; ++ks) {
                int arow = mt * 16 + (ln & 15);
                int aad = (AR_OFF + arow * 128 + ks * 64 + ((ln >> 4) << 4)) ^ ((arow & 7) << 4);
                short8 a = *(const short8*)(smem + aad);
                int bcol = nt * 16 + (ln & 15);
                int bad = (XW_OFF + bcol * 128 + ks * 64 + ((ln >> 4) << 4)) ^ ((bcol & 7) << 4);
                short8 bb = *(const short8*)(smem + bad);
                d = __builtin_amdgcn_mfma_f32_16x16x32_bf16(a, bb, d, 0, 0, 0);
            }
            int col = nt * 16 + (ln & 15);
#pragma unroll
            for (int j = 0; j < 4; ++j) {
                int row = mt * 16 + ((ln >> 4) << 2) + j;
                if (row < N_) outr[row * 64 + col] = fmaxf(d[j], 0.f);
            }
        }
        __syncthreads();
    }
}

// ---------------- gate: wave-private 16-row tiles, loops all t, no barriers ----------------
__launch_bounds__(256, 4)
__global__ void gate_kernel(const float* __restrict__ h0,
                            const unsigned short* __restrict__ wsF,
                            const float* __restrict__ bz, const float* __restrict__ brg,
                            const float* __restrict__ bh,
                            float* out) {
    __shared__ __align__(16) unsigned short bounce[4][16 * 72];
    const int blk = blockIdx.x;
    const int b = blk >> 2;
    const int wv = threadIdx.x >> 6, ln = threadIdx.x & 63;
    const int tile = ((blk & 3) << 2) + wv;
    unsigned short* tb = bounce[wv];
    const size_t TS = (size_t)R_ * B_ * N_ * 64;

    int ga = tile * 16 + (ln & 15); if (ga > 244) ga = 244;
    const size_t aoff = ((size_t)((ga / 35) * B_ + b) * N_ + (ga % 35)) * 64 + ((ln >> 4) << 3);
    const int colb = ln & 15;
    int coff[4]; bool vj[4];
#pragma unroll
    for (int j = 0; j < 4; ++j) {
        int g = tile * 16 + ((ln >> 4) << 2) + j;
        vj[j] = (g < 245);
        int gc = vj[j] ? g : 244;
        coff[j] = (((gc / 35) * B_ + b) * N_ + (gc % 35)) * 64;
    }
    float bzv[4], brv[4], bhv[4];
#pragma unroll
    for (int nt = 0; nt < 4; ++nt) {
        int c = nt * 16 + colb;
        bzv[nt] = bz[c]; brv[nt] = brg[c]; bhv[nt] = bh[c];
    }

    short8 ah[2];
    float hp[4][4];
    {
        const float* hA = h0 + aoff;
#pragma unroll
        for (int ks = 0; ks < 2; ++ks) {
            f32x4 u = *(const f32x4*)(hA + ks * 32);
            f32x4 v = *(const f32x4*)(hA + ks * 32 + 4);
            short8 s;
#pragma unroll
            for (int e = 0; e < 4; ++e) { s[e] = (short)f2bf(u[e]); s[e + 4] = (short)f2bf(v[e]); }
            ah[ks] = s;
        }
#pragma unroll
        for (int nt = 0; nt < 4; ++nt)
#pragma unroll
            for (int j = 0; j < 4; ++j) hp[nt][j] = h0[coff[j] + nt * 16 + colb];
    }
    // prefetch msg for t=0
    f32x4 mp0, mp1, mp2, mp3;
    {
        const float* mA = out + aoff;
        mp0 = *(const f32x4*)(mA);      mp1 = *(const f32x4*)(mA + 4);
        mp2 = *(const f32x4*)(mA + 32); mp3 = *(const f32x4*)(mA + 36);
    }
    const unsigned short* Wl = wsF + ln * 8;

    for (int t = 0; t < T_; ++t) {
        short8 amsg[2];
        {
            short8 s;
#pragma unroll
            for (int e = 0; e < 4; ++e) { s[e] = (short)f2bf(mp0[e]); s[e + 4] = (short)f2bf(mp1[e]); }
            amsg[0] = s;
#pragma unroll
            for (int e = 0; e < 4; ++e) { s[e] = (short)f2bf(mp2[e]); s[e + 4] = (short)f2bf(mp3[e]); }
            amsg[1] = s;
        }
        {   // prefetch next t (clamped; reads untouched msg slab)
            int tn = (t < T_ - 1) ? (t + 1) : (T_ - 1);
            const float* mA = out + (size_t)tn * TS + aoff;
            mp0 = *(const f32x4*)(mA);      mp1 = *(const f32x4*)(mA + 4);
            mp2 = *(const f32x4*)(mA + 32); mp3 = *(const f32x4*)(mA + 36);
        }
        float zC[4][4];
#pragma unroll
        for (int nt = 0; nt < 4; ++nt) {
            f32x4 z  = {bzv[nt], bzv[nt], bzv[nt], bzv[nt]};
            f32x4 rg = {brv[nt], brv[nt], brv[nt], brv[nt]};
#pragma unroll
            for (int ks = 0; ks < 2; ++ks) {
                const unsigned short* wb = Wl + nt * 1024 + ks * 512;
                z  = __builtin_amdgcn_mfma_f32_16x16x32_bf16(amsg[ks], *(const short8*)(wb),         z, 0, 0, 0);
                z  = __builtin_amdgcn_mfma_f32_16x16x32_bf16(ah[ks],   *(const short8*)(wb + 4096),  z, 0, 0, 0);
                rg = __builtin_amdgcn_mfma_f32_16x16x32_bf16(amsg[ks], *(const short8*)(wb + 8192),  rg, 0, 0, 0);
                rg = __builtin_amdgcn_mfma_f32_16x16x32_bf16(ah[ks],   *(const short8*)(wb + 12288), rg, 0, 0, 0);
            }
#pragma unroll
            for (int j = 0; j < 4; ++j) {
                float zv = 1.f / (1.f + __expf(-z[j]));
                float rv = 1.f / (1.f + __expf(-rg[j]));
                zC[nt][j] = zv;
                tb[(((ln >> 4) << 2) + j) * 72 + nt * 16 + colb] = f2bf(rv * hp[nt][j]);
            }
        }
        short8 arh[2];
#pragma unroll
        for (int ks = 0; ks < 2; ++ks)
            arh[ks] = *(const short8*)(tb + (ln & 15) * 72 + ks * 32 + ((ln >> 4) << 3));
        float* outT = out + (size_t)t * TS;
#pragma unroll
        for (int nt = 0; nt < 4; ++nt) {
            f32x4 m = {bhv[nt], bhv[nt], bhv[nt], bhv[nt]};
#pragma unroll
            for (int ks = 0; ks < 2; ++ks) {
                const unsigned short* wb = Wl + nt * 1024 + ks * 512;
                m = __builtin_amdgcn_mfma_f32_16x16x32_bf16(amsg[ks], *(const short8*)(wb + 16384), m, 0, 0, 0);
                m = __builtin_amdgcn_mfma_f32_16x16x32_bf16(arh[ks],  *(const short8*)(wb + 20480), m, 0, 0, 0);
            }
#pragma unroll
            for (int j = 0; j < 4; ++j) {
                float e2 = __expf(2.f * m[j]);
                float th = 1.f - 2.f / (1.f + e2);
                float hn = hp[nt][j] + zC[nt][j] * (th - hp[nt][j]);
                hp[nt][j] = hn;
                if (vj[j]) outT[coff[j] + nt * 16 + colb] = hn;
                tb[(((ln >> 4) << 2) + j) * 72 + nt * 16 + colb] = f2bf(hn);
            }
        }
#pragma unroll
        for (int ks = 0; ks < 2; ++ks)
            ah[ks] = *(const short8*)(tb + (ln & 15) * 72 + ks * 32 + ((ln >> 4) << 3));
    }
}

extern "C" void kernel_launch(void* const* d_in, const int* in_sizes, int n_in,
                              void* d_out, int out_size, void* d_ws, size_t ws_size,
                              hipStream_t stream) {
    const float* x    = (const float*)d_in[0];
    const float* As   = (const float*)d_in[1];
    const float* Af   = (const float*)d_in[2];
    const float* At   = (const float*)d_in[3];
    const float* h0   = (const float*)d_in[4];
    const float* Wq   = (const float*)d_in[5];
    const float* Wk   = (const float*)d_in[6];
    const float* V    = (const float*)d_in[7];
    const float* coef = (const float*)d_in[8];
    const float* Uz   = (const float*)d_in[9];
    const float* Wz   = (const float*)d_in[10];
    const float* bz   = (const float*)d_in[11];
    const float* Ur   = (const float*)d_in[12];
    const float* Wrg  = (const float*)d_in[13];
    const float* brg  = (const float*)d_in[14];
    const float* Uh   = (const float*)d_in[15];
    const float* Wh   = (const float*)d_in[16];
    const float* bh   = (const float*)d_in[17];
    float* out = (float*)d_out;
    unsigned short* wsF = (unsigned short*)d_ws;  // 86016 B used

    hipLaunchKernelGGL(pack_kernel, dim3(168), dim3(256), 0, stream,
                       Wq, Wk, coef, V, Uz, Wz, Ur, Wrg, Uh, Wh, wsF);
    hipLaunchKernelGGL(msg_kernel, dim3(T_ * B_), dim3(512), 0, stream,
                       x, As, Af, At, wsF, out);
    hipLaunchKernelGGL(gate_kernel, dim3(B_ * 4), dim3(256), 0, stream,
                       h0, wsF, bz, brg, bh, out);
}

// Round 5
// 346.271 us; speedup vs baseline: 2.3662x; 2.3662x over previous
//
#include <hip/hip_runtime.h>

typedef short short8 __attribute__((ext_vector_type(8)));
typedef float f32x4 __attribute__((ext_vector_type(4)));

#define T_ 12
#define B_ 256
#define N_ 35
#define M_ 29
#define H_ 64
#define R_ 7

// ---- ws (shorts) layout: packed bf16 MFMA B-fragments ----
// W6F   @0     : 6 mats x [nt4][ks2][64 lanes][8]  = 24576 shorts
// WQKF  @24576 : 2 mats x [nt4][64][8]             = 4096
// WRELF @28672 : 7 r    x [nt4][64][8]             = 14336

// ---- msg_kernel LDS (bytes) ----
#define XFRAG_OFF 0        // 3 mt x [64][16B] bf16 A-frags of x      (3072)
#define Q_OFF     3072     // fp32 [35][64] swz                        (9216)
#define K_OFF     12288    // fp32 [35][64] linear                     (8960)
#define S_OFF     21248    // fp32 [35][36] softmax sum                (5040)
#define AN_OFF    26288    // bf16 [3][35][36]                         (7560)
#define AR_OFF    33920    // bf16 [48][64] swz                        (6144)
#define XW_OFF    40064    // bf16 [64 col][64 k] swz                  (8192)
#define SMEM_A    48256

// ---- gate_kernel dynamic LDS: W6 copy + per-wave bounce ----
#define GATE_BOUNCE_STRIDE 66                    // shorts per row (conflict-free)
#define GATE_LDS (49152 + 16 * 16 * GATE_BOUNCE_STRIDE * 2)   // 49152+33792 = 82944

__device__ __forceinline__ unsigned short f2bf(float f) {
    unsigned int u = __float_as_uint(f);
    u += 0x7fffu + ((u >> 16) & 1u);
    return (unsigned short)(u >> 16);
}
__device__ __forceinline__ float bf2f(unsigned short s) {
    return __uint_as_float(((unsigned int)s) << 16);
}

// ---------------- pack: weights -> bf16 fragment order in ws ----------------
__global__ void pack_kernel(const float* __restrict__ Wq, const float* __restrict__ Wk,
                            const float* __restrict__ coef, const float* __restrict__ V,
                            const float* __restrict__ Uz, const float* __restrict__ Wz,
                            const float* __restrict__ Ur, const float* __restrict__ Wrg,
                            const float* __restrict__ Uh, const float* __restrict__ Wh,
                            unsigned short* __restrict__ ws) {
    int idx = blockIdx.x * 256 + threadIdx.x;   // grid covers exactly 43008
    if (idx < 24576) {                          // W6: mat*4096 + nt*1024 + ks*512 + l*8 + i
        int mat = idx >> 12, rem = idx & 4095;
        int i = rem & 7, l = (rem >> 3) & 63, ks = (rem >> 9) & 1, nt = rem >> 10;
        int j = ks * 32 + ((l >> 4) << 3) + i, c = nt * 16 + (l & 15);
        const float* W = (mat == 0) ? Uz : (mat == 1) ? Wz : (mat == 2) ? Ur
                       : (mat == 3) ? Wrg : (mat == 4) ? Uh : Wh;
        ws[idx] = f2bf(W[j * 64 + c]);
    } else if (idx < 28672) {                   // WQK
        int rem = idx - 24576;
        int mq = rem >> 11; rem &= 2047;
        int i = rem & 7, l = (rem >> 3) & 63, nt = rem >> 9;
        int j = ((l >> 4) << 3) + i, c = nt * 16 + (l & 15);
        const float* W = mq ? Wk : Wq;
        ws[idx] = (j < M_) ? f2bf(W[j * 64 + c]) : (unsigned short)0;
    } else {                                    // WREL
        int rem = idx - 28672;
        int r = rem >> 11; rem &= 2047;
        int i = rem & 7, l = (rem >> 3) & 63, nt = rem >> 9;
        int j = ((l >> 4) << 3) + i, c = nt * 16 + (l & 15);
        unsigned short v = 0;
        if (j < M_) {
            float a = 0.f;
#pragma unroll
            for (int bb = 0; bb < 3; ++bb) a += coef[r * 3 + bb] * V[(bb * M_ + j) * 64 + c];
            v = f2bf(a);
        }
        ws[idx] = v;
    }
}

// ---------------- msg: one block per (t,b); msg fp32 -> out[t] ----------------
__launch_bounds__(512, 4)
__global__ void msg_kernel(const float* __restrict__ x,
                           const float* __restrict__ As, const float* __restrict__ Af,
                           const float* __restrict__ At,
                           const unsigned short* __restrict__ wsF,
                           float* __restrict__ out) {
    __shared__ __align__(16) char smem[SMEM_A];
    const int blk = blockIdx.x;
    const int t = blk >> 8, b = blk & 255;
    const int tid = threadIdx.x, wv = tid >> 6, ln = tid & 63;
    const unsigned short* WQKF  = wsF + 24576;
    const unsigned short* WRELF = wsF + 28672;
    const float* __restrict__ xt = x + ((size_t)t * B_ + b) * (N_ * M_);

    for (int e = tid; e < 1536; e += 512) {
        int mt = e >> 9, l = (e >> 3) & 63, i = e & 7;
        int row = mt * 16 + (l & 15), k = ((l >> 4) << 3) + i;
        float v = (row < N_ && k < M_) ? xt[row * M_ + k] : 0.f;
        *(unsigned short*)(smem + XFRAG_OFF + e * 2) = f2bf(v);
    }
    for (int e = tid; e < 35 * 36; e += 512) *(float*)(smem + S_OFF + e * 4) = 0.f;
    for (int e = tid; e < 3072; e += 512) {
        int row = e >> 6, kk = e & 63;
        if (row >= N_ || kk >= N_) {
            int a = AR_OFF + row * 128 + kk * 2; a ^= (row & 7) << 4;
            *(unsigned short*)(smem + a) = 0;
        }
    }
    for (int e = tid; e < 4096; e += 512) {
        int col = e >> 6, kk = e & 63;
        if (kk >= N_) {
            int a = XW_OFF + col * 128 + kk * 2; a ^= (col & 7) << 4;
            *(unsigned short*)(smem + a) = 0;
        }
    }
    __syncthreads();

    // p2: q = x@Wq (swz fp32), k = x@Wk (linear fp32)
    for (int tile = wv; tile < 24; tile += 8) {
        int qk = (tile >= 12) ? 1 : 0;
        int tt = tile - 12 * qk;
        int mt = tt >> 2, nt = tt & 3;
        short8 a  = *(const short8*)(smem + XFRAG_OFF + (mt * 64 + ln) * 16);
        short8 bb = *(const short8*)(WQKF + (qk * 4 + nt) * 512 + ln * 8);
        f32x4 d = {0.f, 0.f, 0.f, 0.f};
        d = __builtin_amdgcn_mfma_f32_16x16x32_bf16(a, bb, d, 0, 0, 0);
        int col = nt * 16 + (ln & 15);
#pragma unroll
        for (int j = 0; j < 4; ++j) {
            int row = mt * 16 + ((ln >> 4) << 2) + j;
            if (row < N_) {
                if (qk) *(float*)(smem + K_OFF + (row * 64 + col) * 4) = d[j];
                else {
                    int ad = (Q_OFF + row * 256 + col * 4) ^ ((row & 7) << 4);
                    *(float*)(smem + ad) = d[j];
                }
            }
        }
    }
    __syncthreads();

    // p3: wave = head; lane = n-row; broadcast K reads; atomicAdd softmax into S
    {
        const int hd = wv, n = ln, nn = (n < N_) ? n : 34;
        const int qb = Q_OFF + nn * 256 + hd * 32;
        const int swzq = (nn & 7) << 4;
        f32x4 q0 = *(const f32x4*)(smem + (qb ^ swzq));
        f32x4 q1 = *(const f32x4*)(smem + ((qb + 16) ^ swzq));
        float s[35];
#pragma unroll
        for (int m = 0; m < N_; ++m) {
            f32x4 k0 = *(const f32x4*)(smem + K_OFF + (m * 64 + hd * 8) * 4);
            f32x4 k1 = *(const f32x4*)(smem + K_OFF + (m * 64 + hd * 8 + 4) * 4);
            float acc = q0[0]*k0[0] + q0[1]*k0[1] + q0[2]*k0[2] + q0[3]*k0[3]
                      + q1[0]*k1[0] + q1[1]*k1[1] + q1[2]*k1[2] + q1[3]*k1[3];
            s[m] = acc * 0.3535533905932738f;
        }
        float mx = s[0];
#pragma unroll
        for (int m = 1; m < N_; ++m) mx = fmaxf(mx, s[m]);
        float sum = 0.f;
#pragma unroll
        for (int m = 0; m < N_; ++m) { s[m] = __expf(s[m] - mx); sum += s[m]; }
        float inv = 1.f / sum;
        if (n < N_) {
            float* Sp = (float*)(smem + S_OFF) + n * 36;
#pragma unroll
            for (int m = 0; m < N_; ++m) atomicAdd(Sp + m, s[m] * inv);
        }
    }
    __syncthreads();

    // p4: An = l2norm(A * S) along n
    if (tid < 420) {
        int g = tid >> 2, sub = tid & 3;
        int mat = g / N_, j = g - N_ * mat;
        const float* __restrict__ A = (mat == 0) ? As : ((mat == 1) ? Af : At);
        float vals[9]; float ss = 0.f;
#pragma unroll
        for (int i = 0; i < 9; ++i) {
            int n = sub + 4 * i;
            float vv = 0.f;
            if (n < N_) vv = A[n * N_ + j] * *((const float*)(smem + S_OFF) + n * 36 + j);
            vals[i] = vv; ss += vv * vv;
        }
        ss += __shfl_xor(ss, 1);
        ss += __shfl_xor(ss, 2);
        float inv = 1.f / fmaxf(sqrtf(ss), 1e-12f);
#pragma unroll
        for (int i = 0; i < 9; ++i) {
            int n = sub + 4 * i;
            if (n < N_)
                *(unsigned short*)(smem + AN_OFF + (mat * 1260 + n * 36 + j) * 2) = f2bf(vals[i] * inv);
        }
    }
    __syncthreads();

    // p5: per relation: xw = x@Wrel_r, A_r combo, msg = relu(A_r@xw) -> out[t]
    for (int r = 0; r < R_; ++r) {
        float c0, c1, c2;
        switch (r) {
            case 0: c0 = 1.f;  c1 = 0.f;  c2 = 0.f;  break;
            case 1: c0 = 0.f;  c1 = 1.f;  c2 = 0.f;  break;
            case 2: c0 = 0.f;  c1 = 0.f;  c2 = 1.f;  break;
            case 3: c0 = .5f;  c1 = .5f;  c2 = 0.f;  break;
            case 4: c0 = .5f;  c1 = 0.f;  c2 = .5f;  break;
            case 5: c0 = 0.f;  c1 = .5f;  c2 = .5f;  break;
            default: c0 = c1 = c2 = (1.f / 3.f);     break;
        }
        for (int tile = wv; tile < 12; tile += 8) {
            int mt = tile >> 2, nt = tile & 3;
            short8 a  = *(const short8*)(smem + XFRAG_OFF + (mt * 64 + ln) * 16);
            short8 bb = *(const short8*)(WRELF + (r * 4 + nt) * 512 + ln * 8);
            f32x4 d = {0.f, 0.f, 0.f, 0.f};
            d = __builtin_amdgcn_mfma_f32_16x16x32_bf16(a, bb, d, 0, 0, 0);
            int col = nt * 16 + (ln & 15);
#pragma unroll
            for (int j = 0; j < 4; ++j) {
                int krow = mt * 16 + ((ln >> 4) << 2) + j;
                if (krow < N_) {
                    int ad = (XW_OFF + col * 128 + krow * 2) ^ ((col & 7) << 4);
                    *(unsigned short*)(smem + ad) = f2bf(d[j]);
                }
            }
        }
        for (int e = tid; e < 1225; e += 512) {
            int n = e / 35, kk = e % 35;
            float v = c0 * bf2f(*(const unsigned short*)(smem + AN_OFF + (n * 36 + kk) * 2))
                    + c1 * bf2f(*(const unsigned short*)(smem + AN_OFF + (1260 + n * 36 + kk) * 2))
                    + c2 * bf2f(*(const unsigned short*)(smem + AN_OFF + (2520 + n * 36 + kk) * 2));
            int ad = (AR_OFF + n * 128 + kk * 2) ^ ((n & 7) << 4);
            *(unsigned short*)(smem + ad) = f2bf(v);
        }
        __syncthreads();
        float* __restrict__ outr = out + (((size_t)t * R_ + r) * B_ + b) * (N_ * 64);
        for (int tile = wv; tile < 12; tile += 8) {
            int mt = tile >> 2, nt = tile & 3;
            f32x4 d = {0.f, 0.f, 0.f, 0.f};
#pragma unroll
            for (int ks = 0; ks < 2; ++ks) {
                int arow = mt * 16 + (ln & 15);
                int aad = (AR_OFF + arow * 128 + ks * 64 + ((ln >> 4) << 4)) ^ ((arow & 7) << 4);
                short8 a = *(const short8*)(smem + aad);
                int bcol = nt * 16 + (ln & 15);
                int bad = (XW_OFF + bcol * 128 + ks * 64 + ((ln >> 4) << 4)) ^ ((bcol & 7) << 4);
                short8 bb = *(const short8*)(smem + bad);
                d = __builtin_amdgcn_mfma_f32_16x16x32_bf16(a, bb, d, 0, 0, 0);
            }
            int col = nt * 16 + (ln & 15);
#pragma unroll
            for (int j = 0; j < 4; ++j) {
                int row = mt * 16 + ((ln >> 4) << 2) + j;
                if (row < N_) outr[row * 64 + col] = fmaxf(d[j], 0.f);
            }
        }
        __syncthreads();
    }
}

// -------- gate: 1 block per b, 16 waves = 16 tiles, weights in LDS, no t-loop barriers --------
__launch_bounds__(1024, 1)
__global__ void gate_kernel(const float* __restrict__ h0,
                            const unsigned short* __restrict__ wsF,
                            const float* __restrict__ bz, const float* __restrict__ brg,
                            const float* __restrict__ bh,
                            float* out) {
    extern __shared__ char gsm[];
    unsigned short* W6L = (unsigned short*)gsm;                   // 24576 shorts
    const int tid = threadIdx.x;
    const int wv = tid >> 6, ln = tid & 63;
    const int b = blockIdx.x;
    const int tile = wv;                                          // 16 tiles
    unsigned short* tb = (unsigned short*)(gsm + 49152) + wv * (16 * GATE_BOUNCE_STRIDE);
    const size_t TS = (size_t)R_ * B_ * N_ * 64;

    // stage all 6 GRU weight matrices' B-frags into LDS (once)
    for (int e = tid; e < 3072; e += 1024)
        ((short8*)W6L)[e] = ((const short8*)wsF)[e];
    __syncthreads();

    int ga = tile * 16 + (ln & 15); if (ga > 244) ga = 244;
    const size_t aoff = ((size_t)((ga / 35) * B_ + b) * N_ + (ga % 35)) * 64 + ((ln >> 4) << 3);
    const int colb = ln & 15;
    int coff[4]; bool vj[4];
#pragma unroll
    for (int j = 0; j < 4; ++j) {
        int g = tile * 16 + ((ln >> 4) << 2) + j;
        vj[j] = (g < 245);
        int gc = vj[j] ? g : 244;
        coff[j] = (((gc / 35) * B_ + b) * N_ + (gc % 35)) * 64;
    }
    float bzv[4], brv[4], bhv[4];
#pragma unroll
    for (int nt = 0; nt < 4; ++nt) {
        int c = nt * 16 + colb;
        bzv[nt] = bz[c]; brv[nt] = brg[c]; bhv[nt] = bh[c];
    }

    short8 ah[2];
    float hp[4][4];
    {
        const float* hA = h0 + aoff;
#pragma unroll
        for (int ks = 0; ks < 2; ++ks) {
            f32x4 u = *(const f32x4*)(hA + ks * 32);
            f32x4 v = *(const f32x4*)(hA + ks * 32 + 4);
            short8 s;
#pragma unroll
            for (int e = 0; e < 4; ++e) { s[e] = (short)f2bf(u[e]); s[e + 4] = (short)f2bf(v[e]); }
            ah[ks] = s;
        }
#pragma unroll
        for (int nt = 0; nt < 4; ++nt)
#pragma unroll
            for (int j = 0; j < 4; ++j) hp[nt][j] = h0[coff[j] + nt * 16 + colb];
    }
    // prefetch msg for t=0
    f32x4 mp0, mp1, mp2, mp3;
    {
        const float* mA = out + aoff;
        mp0 = *(const f32x4*)(mA);      mp1 = *(const f32x4*)(mA + 4);
        mp2 = *(const f32x4*)(mA + 32); mp3 = *(const f32x4*)(mA + 36);
    }
    const unsigned short* Wl = W6L + ln * 8;

    for (int t = 0; t < T_; ++t) {
        short8 amsg[2];
        {
            short8 s;
#pragma unroll
            for (int e = 0; e < 4; ++e) { s[e] = (short)f2bf(mp0[e]); s[e + 4] = (short)f2bf(mp1[e]); }
            amsg[0] = s;
#pragma unroll
            for (int e = 0; e < 4; ++e) { s[e] = (short)f2bf(mp2[e]); s[e + 4] = (short)f2bf(mp3[e]); }
            amsg[1] = s;
        }
        {   // prefetch next t's msg
            int tn = (t < T_ - 1) ? (t + 1) : (T_ - 1);
            const float* mA = out + (size_t)tn * TS + aoff;
            mp0 = *(const f32x4*)(mA);      mp1 = *(const f32x4*)(mA + 4);
            mp2 = *(const f32x4*)(mA + 32); mp3 = *(const f32x4*)(mA + 36);
        }
        float zC[4][4];
#pragma unroll
        for (int nt = 0; nt < 4; ++nt) {
            f32x4 z  = {bzv[nt], bzv[nt], bzv[nt], bzv[nt]};
            f32x4 rg = {brv[nt], brv[nt], brv[nt], brv[nt]};
#pragma unroll
            for (int ks = 0; ks < 2; ++ks) {
                const unsigned short* wb = Wl + nt * 1024 + ks * 512;
                z  = __builtin_amdgcn_mfma_f32_16x16x32_bf16(amsg[ks], *(const short8*)(wb),         z, 0, 0, 0);
                z  = __builtin_amdgcn_mfma_f32_16x16x32_bf16(ah[ks],   *(const short8*)(wb + 4096),  z, 0, 0, 0);
                rg = __builtin_amdgcn_mfma_f32_16x16x32_bf16(amsg[ks], *(const short8*)(wb + 8192),  rg, 0, 0, 0);
                rg = __builtin_amdgcn_mfma_f32_16x16x32_bf16(ah[ks],   *(const short8*)(wb + 12288), rg, 0, 0, 0);
            }
#pragma unroll
            for (int j = 0; j < 4; ++j) {
                float zv = 1.f / (1.f + __expf(-z[j]));
                float rv = 1.f / (1.f + __expf(-rg[j]));
                zC[nt][j] = zv;
                tb[(((ln >> 4) << 2) + j) * GATE_BOUNCE_STRIDE + nt * 16 + colb] = f2bf(rv * hp[nt][j]);
            }
        }
        short8 arh[2];
#pragma unroll
        for (int ks = 0; ks < 2; ++ks)
            arh[ks] = *(const short8*)(tb + (ln & 15) * GATE_BOUNCE_STRIDE + ks * 32 + ((ln >> 4) << 3));
        float* outT = out + (size_t)t * TS;
#pragma unroll
        for (int nt = 0; nt < 4; ++nt) {
            f32x4 m = {bhv[nt], bhv[nt], bhv[nt], bhv[nt]};
#pragma unroll
            for (int ks = 0; ks < 2; ++ks) {
                const unsigned short* wb = Wl + nt * 1024 + ks * 512;
                m = __builtin_amdgcn_mfma_f32_16x16x32_bf16(amsg[ks], *(const short8*)(wb + 16384), m, 0, 0, 0);
                m = __builtin_amdgcn_mfma_f32_16x16x32_bf16(arh[ks],  *(const short8*)(wb + 20480), m, 0, 0, 0);
            }
#pragma unroll
            for (int j = 0; j < 4; ++j) {
                float e2 = __expf(2.f * m[j]);
                float th = 1.f - 2.f / (1.f + e2);
                float hn = hp[nt][j] + zC[nt][j] * (th - hp[nt][j]);
                hp[nt][j] = hn;
                if (vj[j]) outT[coff[j] + nt * 16 + colb] = hn;
                tb[(((ln >> 4) << 2) + j) * GATE_BOUNCE_STRIDE + nt * 16 + colb] = f2bf(hn);
            }
        }
#pragma unroll
        for (int ks = 0; ks < 2; ++ks)
            ah[ks] = *(const short8*)(tb + (ln & 15) * GATE_BOUNCE_STRIDE + ks * 32 + ((ln >> 4) << 3));
    }
}

extern "C" void kernel_launch(void* const* d_in, const int* in_sizes, int n_in,
                              void* d_out, int out_size, void* d_ws, size_t ws_size,
                              hipStream_t stream) {
    const float* x    = (const float*)d_in[0];
    const float* As   = (const float*)d_in[1];
    const float* Af   = (const float*)d_in[2];
    const float* At   = (const float*)d_in[3];
    const float* h0   = (const float*)d_in[4];
    const float* Wq   = (const float*)d_in[5];
    const float* Wk   = (const float*)d_in[6];
    const float* V    = (const float*)d_in[7];
    const float* coef = (const float*)d_in[8];
    const float* Uz   = (const float*)d_in[9];
    const float* Wz   = (const float*)d_in[10];
    const float* bz   = (const float*)d_in[11];
    const float* Ur   = (const float*)d_in[12];
    const float* Wrg  = (const float*)d_in[13];
    const float* brg  = (const float*)d_in[14];
    const float* Uh   = (const float*)d_in[15];
    const float* Wh   = (const float*)d_in[16];
    const float* bh   = (const float*)d_in[17];
    float* out = (float*)d_out;
    unsigned short* wsF = (unsigned short*)d_ws;  // 86016 B used

    hipFuncSetAttribute((const void*)gate_kernel,
                        hipFuncAttributeMaxDynamicSharedMemorySize, GATE_LDS);

    hipLaunchKernelGGL(pack_kernel, dim3(168), dim3(256), 0, stream,
                       Wq, Wk, coef, V, Uz, Wz, Ur, Wrg, Uh, Wh, wsF);
    hipLaunchKernelGGL(msg_kernel, dim3(T_ * B_), dim3(512), 0, stream,
                       x, As, Af, At, wsF, out);
    hipLaunchKernelGGL(gate_kernel, dim3(B_), dim3(1024), GATE_LDS, stream,
                       h0, wsF, bz, brg, bh, out);
}

// Round 6
// 330.534 us; speedup vs baseline: 2.4788x; 1.0476x over previous
//
#include <hip/hip_runtime.h>

typedef short short8 __attribute__((ext_vector_type(8)));
typedef float f32x4 __attribute__((ext_vector_type(4)));

#define T_ 12
#define B_ 256
#define N_ 35
#define M_ 29
#define H_ 64
#define R_ 7

// ---- ws (shorts) layout: packed bf16 MFMA B-fragments ----
// W6F   @0     : 6 mats x [nt4][ks2][64 lanes][8]  = 24576 shorts
// WQKF  @24576 : 2 mats x [nt4][64][8]             = 4096
// WRELF @28672 : 7 r    x [nt4][64][8]             = 14336

// ---- msg_kernel static LDS (bytes), phase-overlaid pool ----
#define XA_OFF   0        // x A-frags: 3 mt x [64][8] bf16              (3072)
#define XB_OFF   3072     // x B-frags: [ks2][nt2][64][8] bf16           (4096)
#define Q_OFF    7168     // fp32 [35][64] swz (p2-p3)                   (9216)
#define K_OFF    16384    // fp32 [35][64] linear (p2-p3)                (8960)
#define S_OFF    25344    // fp32 [35][36] softmax sum (p0-p4)           (5040)
#define AN_OFF   7168     // bf16 [3][35][40] (p4-p5a) overlays Q        (8400)
#define AXF_OFF  15568    // bf16 ax A-frags [7r][3mt][64][8] (p5a-p5b)  (21504)
#define SMEM_A   37120

__device__ __forceinline__ unsigned short f2bf(float f) {
    unsigned int u = __float_as_uint(f);
    u += 0x7fffu + ((u >> 16) & 1u);
    return (unsigned short)(u >> 16);
}
__device__ __forceinline__ float bf2f(unsigned short s) {
    return __uint_as_float(((unsigned int)s) << 16);
}

// ---------------- pack: weights -> bf16 fragment order in ws ----------------
__global__ void pack_kernel(const float* __restrict__ Wq, const float* __restrict__ Wk,
                            const float* __restrict__ coef, const float* __restrict__ V,
                            const float* __restrict__ Uz, const float* __restrict__ Wz,
                            const float* __restrict__ Ur, const float* __restrict__ Wrg,
                            const float* __restrict__ Uh, const float* __restrict__ Wh,
                            unsigned short* __restrict__ ws) {
    int idx = blockIdx.x * 256 + threadIdx.x;   // grid covers exactly 43008
    if (idx < 24576) {                          // W6
        int mat = idx >> 12, rem = idx & 4095;
        int i = rem & 7, l = (rem >> 3) & 63, ks = (rem >> 9) & 1, nt = rem >> 10;
        int j = ks * 32 + ((l >> 4) << 3) + i, c = nt * 16 + (l & 15);
        const float* W = (mat == 0) ? Uz : (mat == 1) ? Wz : (mat == 2) ? Ur
                       : (mat == 3) ? Wrg : (mat == 4) ? Uh : Wh;
        ws[idx] = f2bf(W[j * 64 + c]);
    } else if (idx < 28672) {                   // WQK
        int rem = idx - 24576;
        int mq = rem >> 11; rem &= 2047;
        int i = rem & 7, l = (rem >> 3) & 63, nt = rem >> 9;
        int j = ((l >> 4) << 3) + i, c = nt * 16 + (l & 15);
        const float* W = mq ? Wk : Wq;
        ws[idx] = (j < M_) ? f2bf(W[j * 64 + c]) : (unsigned short)0;
    } else {                                    // WREL
        int rem = idx - 28672;
        int r = rem >> 11; rem &= 2047;
        int i = rem & 7, l = (rem >> 3) & 63, nt = rem >> 9;
        int j = ((l >> 4) << 3) + i, c = nt * 16 + (l & 15);
        unsigned short v = 0;
        if (j < M_) {
            float a = 0.f;
#pragma unroll
            for (int bb = 0; bb < 3; ++bb) a += coef[r * 3 + bb] * V[(bb * M_ + j) * 64 + c];
            v = f2bf(a);
        }
        ws[idx] = v;
    }
}

// ---------------- msg: one block per (t,b); msg fp32 -> out[t] ----------------
__launch_bounds__(512, 4)
__global__ void msg_kernel(const float* __restrict__ x,
                           const float* __restrict__ As, const float* __restrict__ Af,
                           const float* __restrict__ At,
                           const unsigned short* __restrict__ wsF,
                           float* __restrict__ out) {
    __shared__ __align__(16) char smem[SMEM_A];
    const int blk = blockIdx.x;
    const int t = blk >> 8, b = blk & 255;
    const int tid = threadIdx.x, wv = tid >> 6, ln = tid & 63;
    const unsigned short* WQKF  = wsF + 24576;
    const unsigned short* WRELF = wsF + 28672;
    const float* __restrict__ xt = x + ((size_t)t * B_ + b) * (N_ * M_);

    // ---- p0: stage x A-frags + B-frags; zero S ----
    for (int e = tid; e < 1536; e += 512) {   // A-frags: row=n, k=feature m
        int mt = e >> 9, l = (e >> 3) & 63, i = e & 7;
        int row = mt * 16 + (l & 15), k = ((l >> 4) << 3) + i;
        float v = (row < N_ && k < M_) ? xt[row * M_ + k] : 0.f;
        *(unsigned short*)(smem + XA_OFF + e * 2) = f2bf(v);
    }
    for (int e = tid; e < 2048; e += 512) {   // B-frags: k=node index, c=feature
        int g = e >> 9, l = (e >> 3) & 63, i = e & 7;
        int ks = g >> 1, nt = g & 1;
        int k = ks * 32 + ((l >> 4) << 3) + i, c = nt * 16 + (l & 15);
        float v = (k < N_ && c < M_) ? xt[k * M_ + c] : 0.f;
        *(unsigned short*)(smem + XB_OFF + e * 2) = f2bf(v);
    }
    for (int e = tid; e < 35 * 36; e += 512) *(float*)(smem + S_OFF + e * 4) = 0.f;
    __syncthreads();

    // ---- p2: q = x@Wq (swz fp32), k = x@Wk (linear fp32) ----
    for (int tile = wv; tile < 24; tile += 8) {
        int qk = (tile >= 12) ? 1 : 0;
        int tt = tile - 12 * qk;
        int mt = tt >> 2, nt = tt & 3;
        short8 a  = *(const short8*)(smem + XA_OFF + (mt * 64 + ln) * 16);
        short8 bb = *(const short8*)(WQKF + (qk * 4 + nt) * 512 + ln * 8);
        f32x4 d = {0.f, 0.f, 0.f, 0.f};
        d = __builtin_amdgcn_mfma_f32_16x16x32_bf16(a, bb, d, 0, 0, 0);
        int col = nt * 16 + (ln & 15);
#pragma unroll
        for (int j = 0; j < 4; ++j) {
            int row = mt * 16 + ((ln >> 4) << 2) + j;
            if (row < N_) {
                if (qk) *(float*)(smem + K_OFF + (row * 64 + col) * 4) = d[j];
                else {
                    int ad = (Q_OFF + row * 256 + col * 4) ^ ((row & 7) << 4);
                    *(float*)(smem + ad) = d[j];
                }
            }
        }
    }
    __syncthreads();

    // ---- p3: wave = head; lane = n-row; atomicAdd softmax into S ----
    {
        const int hd = wv, n = ln, nn = (n < N_) ? n : 34;
        const int qb = Q_OFF + nn * 256 + hd * 32;
        const int swzq = (nn & 7) << 4;
        f32x4 q0 = *(const f32x4*)(smem + (qb ^ swzq));
        f32x4 q1 = *(const f32x4*)(smem + ((qb + 16) ^ swzq));
        float s[35];
#pragma unroll
        for (int m = 0; m < N_; ++m) {
            f32x4 k0 = *(const f32x4*)(smem + K_OFF + (m * 64 + hd * 8) * 4);
            f32x4 k1 = *(const f32x4*)(smem + K_OFF + (m * 64 + hd * 8 + 4) * 4);
            float acc = q0[0]*k0[0] + q0[1]*k0[1] + q0[2]*k0[2] + q0[3]*k0[3]
                      + q1[0]*k1[0] + q1[1]*k1[1] + q1[2]*k1[2] + q1[3]*k1[3];
            s[m] = acc * 0.3535533905932738f;
        }
        float mx = s[0];
#pragma unroll
        for (int m = 1; m < N_; ++m) mx = fmaxf(mx, s[m]);
        float sum = 0.f;
#pragma unroll
        for (int m = 0; m < N_; ++m) { s[m] = __expf(s[m] - mx); sum += s[m]; }
        float inv = 1.f / sum;
        if (n < N_) {
            float* Sp = (float*)(smem + S_OFF) + n * 36;
#pragma unroll
            for (int m = 0; m < N_; ++m) atomicAdd(Sp + m, s[m] * inv);
        }
    }
    __syncthreads();

    // ---- p4: An = l2norm(A * S) along n -> bf16 [3][35][40]; zero pad cols ----
    if (tid < 420) {
        int g = tid >> 2, sub = tid & 3;
        int mat = g / N_, j = g - N_ * mat;
        const float* __restrict__ A = (mat == 0) ? As : ((mat == 1) ? Af : At);
        float vals[9]; float ss = 0.f;
#pragma unroll
        for (int i = 0; i < 9; ++i) {
            int n = sub + 4 * i;
            float vv = 0.f;
            if (n < N_) vv = A[n * N_ + j] * *((const float*)(smem + S_OFF) + n * 36 + j);
            vals[i] = vv; ss += vv * vv;
        }
        ss += __shfl_xor(ss, 1);
        ss += __shfl_xor(ss, 2);
        float inv = 1.f / fmaxf(sqrtf(ss), 1e-12f);
#pragma unroll
        for (int i = 0; i < 9; ++i) {
            int n = sub + 4 * i;
            if (n < N_)
                *(unsigned short*)(smem + AN_OFF + ((mat * 35 + n) * 40 + j) * 2) = f2bf(vals[i] * inv);
        }
    }
    for (int e = tid; e < 525; e += 512) {    // pad cols 35..39 of each An row
        int mat = e / 175, rem = e - mat * 175;
        int n = rem / 5, pc = rem - n * 5;
        *(unsigned short*)(smem + AN_OFF + ((mat * 35 + n) * 40 + 35 + pc) * 2) = 0;
    }
    __syncthreads();

    // ---- p5a: ax_r = A_r @ x for ALL r in parallel; A_r frags built on the fly ----
    for (int g = wv; g < 21; g += 8) {
        int r = g / 3, mt = g - 3 * r;
        float c0, c1, c2;
        switch (r) {
            case 0: c0 = 1.f;  c1 = 0.f;  c2 = 0.f;  break;
            case 1: c0 = 0.f;  c1 = 1.f;  c2 = 0.f;  break;
            case 2: c0 = 0.f;  c1 = 0.f;  c2 = 1.f;  break;
            case 3: c0 = .5f;  c1 = .5f;  c2 = 0.f;  break;
            case 4: c0 = .5f;  c1 = 0.f;  c2 = .5f;  break;
            case 5: c0 = 0.f;  c1 = .5f;  c2 = .5f;  break;
            default: c0 = c1 = c2 = (1.f / 3.f);     break;
        }
        const int row = mt * 16 + (ln & 15);
        const float validf = (row < N_) ? 1.f : 0.f;
        const int rowc = (row < N_) ? row : 34;
        short8 aF[2];
#pragma unroll
        for (int ks = 0; ks < 2; ++ks) {
            int k0 = ks * 32 + ((ln >> 4) << 3);
            int k0c = (k0 <= 32) ? k0 : 32;           // clamp (masked below)
            float kmask = (k0 <= 32) ? validf : 0.f;
            short8 a0 = *(const short8*)(smem + AN_OFF + (rowc * 40 + k0c) * 2);
            short8 a1 = *(const short8*)(smem + AN_OFF + ((35 + rowc) * 40 + k0c) * 2);
            short8 a2 = *(const short8*)(smem + AN_OFF + ((70 + rowc) * 40 + k0c) * 2);
            short8 f;
#pragma unroll
            for (int i = 0; i < 8; ++i) {
                float v = c0 * bf2f((unsigned short)a0[i])
                        + c1 * bf2f((unsigned short)a1[i])
                        + c2 * bf2f((unsigned short)a2[i]);
                f[i] = (short)f2bf(v * kmask);
            }
            aF[ks] = f;
        }
#pragma unroll
        for (int nt = 0; nt < 2; ++nt) {
            f32x4 d = {0.f, 0.f, 0.f, 0.f};
#pragma unroll
            for (int ks = 0; ks < 2; ++ks) {
                short8 bb = *(const short8*)(smem + XB_OFF + ((ks * 2 + nt) * 64 + ln) * 16);
                d = __builtin_amdgcn_mfma_f32_16x16x32_bf16(aF[ks], bb, d, 0, 0, 0);
            }
            // scatter D into AXF A-frag layout: element (n, k=c)
#pragma unroll
            for (int j = 0; j < 4; ++j) {
                int nl = ((ln >> 4) << 2) + j;            // n & 15
                int c = nt * 16 + (ln & 15);
                int lp = nl | ((c >> 3) << 4);
                *(unsigned short*)(smem + AXF_OFF + (((r * 3 + mt) * 64 + lp) * 8 + (c & 7)) * 2)
                    = f2bf(d[j]);
            }
        }
    }
    __syncthreads();

    // ---- p5b: msg_r = relu(ax_r @ Wrel_r) for ALL r -> out[t] ----
    for (int tile = wv; tile < 84; tile += 8) {
        int r = tile / 12, rem = tile - 12 * r;
        int mt = rem >> 2, nt = rem & 3;
        short8 a  = *(const short8*)(smem + AXF_OFF + ((r * 3 + mt) * 64 + ln) * 16);
        short8 bb = *(const short8*)(WRELF + (r * 4 + nt) * 512 + ln * 8);
        f32x4 d = {0.f, 0.f, 0.f, 0.f};
        d = __builtin_amdgcn_mfma_f32_16x16x32_bf16(a, bb, d, 0, 0, 0);
        float* __restrict__ outr = out + (((size_t)t * R_ + r) * B_ + b) * (N_ * 64);
        int col = nt * 16 + (ln & 15);
#pragma unroll
        for (int j = 0; j < 4; ++j) {
            int row = mt * 16 + ((ln >> 4) << 2) + j;
            if (row < N_) outr[row * 64 + col] = fmaxf(d[j], 0.f);
        }
    }
}

// ---- gate_kernel dynamic LDS: W6 copy + per-wave bounce ----
#define GATE_BOUNCE_STRIDE 66
#define GATE_LDS (49152 + 16 * 16 * GATE_BOUNCE_STRIDE * 2)   // 82944

__launch_bounds__(1024, 1)
__global__ void gate_kernel(const float* __restrict__ h0,
                            const unsigned short* __restrict__ wsF,
                            const float* __restrict__ bz, const float* __restrict__ brg,
                            const float* __restrict__ bh,
                            float* out) {
    extern __shared__ char gsm[];
    unsigned short* W6L = (unsigned short*)gsm;
    const int tid = threadIdx.x;
    const int wv = tid >> 6, ln = tid & 63;
    const int b = blockIdx.x;
    const int tile = wv;
    unsigned short* tb = (unsigned short*)(gsm + 49152) + wv * (16 * GATE_BOUNCE_STRIDE);
    const size_t TS = (size_t)R_ * B_ * N_ * 64;

    for (int e = tid; e < 3072; e += 1024)
        ((short8*)W6L)[e] = ((const short8*)wsF)[e];
    __syncthreads();

    int ga = tile * 16 + (ln & 15); if (ga > 244) ga = 244;
    const size_t aoff = ((size_t)((ga / 35) * B_ + b) * N_ + (ga % 35)) * 64 + ((ln >> 4) << 3);
    const int colb = ln & 15;
    int coff[4]; bool vj[4];
#pragma unroll
    for (int j = 0; j < 4; ++j) {
        int g = tile * 16 + ((ln >> 4) << 2) + j;
        vj[j] = (g < 245);
        int gc = vj[j] ? g : 244;
        coff[j] = (((gc / 35) * B_ + b) * N_ + (gc % 35)) * 64;
    }
    float bzv[4], brv[4], bhv[4];
#pragma unroll
    for (int nt = 0; nt < 4; ++nt) {
        int c = nt * 16 + colb;
        bzv[nt] = bz[c]; brv[nt] = brg[c]; bhv[nt] = bh[c];
    }

    short8 ah[2];
    float hp[4][4];
    {
        const float* hA = h0 + aoff;
#pragma unroll
        for (int ks = 0; ks < 2; ++ks) {
            f32x4 u = *(const f32x4*)(hA + ks * 32);
            f32x4 v = *(const f32x4*)(hA + ks * 32 + 4);
            short8 s;
#pragma unroll
            for (int e = 0; e < 4; ++e) { s[e] = (short)f2bf(u[e]); s[e + 4] = (short)f2bf(v[e]); }
            ah[ks] = s;
        }
#pragma unroll
        for (int nt = 0; nt < 4; ++nt)
#pragma unroll
            for (int j = 0; j < 4; ++j) hp[nt][j] = h0[coff[j] + nt * 16 + colb];
    }
    f32x4 mp0, mp1, mp2, mp3;
    {
        const float* mA = out + aoff;
        mp0 = *(const f32x4*)(mA);      mp1 = *(const f32x4*)(mA + 4);
        mp2 = *(const f32x4*)(mA + 32); mp3 = *(const f32x4*)(mA + 36);
    }
    const unsigned short* Wl = W6L + ln * 8;

    for (int t = 0; t < T_; ++t) {
        short8 amsg[2];
        {
            short8 s;
#pragma unroll
            for (int e = 0; e < 4; ++e) { s[e] = (short)f2bf(mp0[e]); s[e + 4] = (short)f2bf(mp1[e]); }
            amsg[0] = s;
#pragma unroll
            for (int e = 0; e < 4; ++e) { s[e] = (short)f2bf(mp2[e]); s[e + 4] = (short)f2bf(mp3[e]); }
            amsg[1] = s;
        }
        {
            int tn = (t < T_ - 1) ? (t + 1) : (T_ - 1);
            const float* mA = out + (size_t)tn * TS + aoff;
            mp0 = *(const f32x4*)(mA);      mp1 = *(const f32x4*)(mA + 4);
            mp2 = *(const f32x4*)(mA + 32); mp3 = *(const f32x4*)(mA + 36);
        }
        float zC[4][4];
#pragma unroll
        for (int nt = 0; nt < 4; ++nt) {
            f32x4 z  = {bzv[nt], bzv[nt], bzv[nt], bzv[nt]};
            f32x4 rg = {brv[nt], brv[nt], brv[nt], brv[nt]};
#pragma unroll
            for (int ks = 0; ks < 2; ++ks) {
                const unsigned short* wb = Wl + nt * 1024 + ks * 512;
                z  = __builtin_amdgcn_mfma_f32_16x16x32_bf16(amsg[ks], *(const short8*)(wb),         z, 0, 0, 0);
                z  = __builtin_amdgcn_mfma_f32_16x16x32_bf16(ah[ks],   *(const short8*)(wb + 4096),  z, 0, 0, 0);
                rg = __builtin_amdgcn_mfma_f32_16x16x32_bf16(amsg[ks], *(const short8*)(wb + 8192),  rg, 0, 0, 0);
                rg = __builtin_amdgcn_mfma_f32_16x16x32_bf16(ah[ks],   *(const short8*)(wb + 12288), rg, 0, 0, 0);
            }
#pragma unroll
            for (int j = 0; j < 4; ++j) {
                float zv = 1.f / (1.f + __expf(-z[j]));
                float rv = 1.f / (1.f + __expf(-rg[j]));
                zC[nt][j] = zv;
                tb[(((ln >> 4) << 2) + j) * GATE_BOUNCE_STRIDE + nt * 16 + colb] = f2bf(rv * hp[nt][j]);
            }
        }
        short8 arh[2];
#pragma unroll
        for (int ks = 0; ks < 2; ++ks)
            arh[ks] = *(const short8*)(tb + (ln & 15) * GATE_BOUNCE_STRIDE + ks * 32 + ((ln >> 4) << 3));
        float* outT = out + (size_t)t * TS;
#pragma unroll
        for (int nt = 0; nt < 4; ++nt) {
            f32x4 m = {bhv[nt], bhv[nt], bhv[nt], bhv[nt]};
#pragma unroll
            for (int ks = 0; ks < 2; ++ks) {
                const unsigned short* wb = Wl + nt * 1024 + ks * 512;
                m = __builtin_amdgcn_mfma_f32_16x16x32_bf16(amsg[ks], *(const short8*)(wb + 16384), m, 0, 0, 0);
                m = __builtin_amdgcn_mfma_f32_16x16x32_bf16(arh[ks],  *(const short8*)(wb + 20480), m, 0, 0, 0);
            }
#pragma unroll
            for (int j = 0; j < 4; ++j) {
                float e2 = __expf(2.f * m[j]);
                float th = 1.f - 2.f / (1.f + e2);
                float hn = hp[nt][j] + zC[nt][j] * (th - hp[nt][j]);
                hp[nt][j] = hn;
                if (vj[j]) outT[coff[j] + nt * 16 + colb] = hn;
                tb[(((ln >> 4) << 2) + j) * GATE_BOUNCE_STRIDE + nt * 16 + colb] = f2bf(hn);
            }
        }
#pragma unroll
        for (int ks = 0; ks < 2; ++ks)
            ah[ks] = *(const short8*)(tb + (ln & 15) * GATE_BOUNCE_STRIDE + ks * 32 + ((ln >> 4) << 3));
    }
}

extern "C" void kernel_launch(void* const* d_in, const int* in_sizes, int n_in,
                              void* d_out, int out_size, void* d_ws, size_t ws_size,
                              hipStream_t stream) {
    const float* x    = (const float*)d_in[0];
    const float* As   = (const float*)d_in[1];
    const float* Af   = (const float*)d_in[2];
    const float* At   = (const float*)d_in[3];
    const float* h0   = (const float*)d_in[4];
    const float* Wq   = (const float*)d_in[5];
    const float* Wk   = (const float*)d_in[6];
    const float* V    = (const float*)d_in[7];
    const float* coef = (const float*)d_in[8];
    const float* Uz   = (const float*)d_in[9];
    const float* Wz   = (const float*)d_in[10];
    const float* bz   = (const float*)d_in[11];
    const float* Ur   = (const float*)d_in[12];
    const float* Wrg  = (const float*)d_in[13];
    const float* brg  = (const float*)d_in[14];
    const float* Uh   = (const float*)d_in[15];
    const float* Wh   = (const float*)d_in[16];
    const float* bh   = (const float*)d_in[17];
    float* out = (float*)d_out;
    unsigned short* wsF = (unsigned short*)d_ws;  // 86016 B used

    hipFuncSetAttribute((const void*)gate_kernel,
                        hipFuncAttributeMaxDynamicSharedMemorySize, GATE_LDS);

    hipLaunchKernelGGL(pack_kernel, dim3(168), dim3(256), 0, stream,
                       Wq, Wk, coef, V, Uz, Wz, Ur, Wrg, Uh, Wh, wsF);
    hipLaunchKernelGGL(msg_kernel, dim3(T_ * B_), dim3(512), 0, stream,
                       x, As, Af, At, wsF, out);
    hipLaunchKernelGGL(gate_kernel, dim3(B_), dim3(1024), GATE_LDS, stream,
                       h0, wsF, bz, brg, bh, out);
}

// Round 7
// 312.385 us; speedup vs baseline: 2.6228x; 1.0581x over previous
//
#include <hip/hip_runtime.h>

typedef short short8 __attribute__((ext_vector_type(8)));
typedef float f32x4 __attribute__((ext_vector_type(4)));

#define T_ 12
#define B_ 256
#define N_ 35
#define M_ 29
#define H_ 64
#define R_ 7

// ---- ws (shorts) layout: packed bf16 MFMA B-fragments ----
// W6F   @0     : 6 mats x [nt4][ks2][64 lanes][8]  = 24576 shorts
// WQKF  @24576 : 2 mats x [nt4][64][8]             = 4096
// WRELF @28672 : 7 r    x [nt4][64][8]             = 14336

// ---- msg_kernel static LDS (bytes), phase-overlaid ----
#define XA_OFF   0        // x A-frags: 3 mt x [64][8] bf16          (3072)
#define XB_OFF   3072     // x B-frags: [ks2][nt2][64][8] bf16       (4096)  dead after p5a
#define Q_OFF    7168     // fp32 [35][64] swz (p2-p3)               (9216)
#define K_OFF    16384    // fp32 [35][64] linear (p2-p3)            (8960)
#define S_OFF    25344    // fp32 [35][36] softmax sum (p0-p4)       (5040)
#define AN_OFF   7168     // bf16 [3][35][40] (p4-p5a) over Q        (8400)
#define AXB_OFF  16384    // fp32 [3][35][44] base products, over K  (18480)
#define SMEM_A   34864

__device__ __forceinline__ unsigned short f2bf(float f) {
    unsigned int u = __float_as_uint(f);
    u += 0x7fffu + ((u >> 16) & 1u);
    return (unsigned short)(u >> 16);
}
__device__ __forceinline__ float bf2f(unsigned short s) {
    return __uint_as_float(((unsigned int)s) << 16);
}

// ---------------- pack: weights -> bf16 fragment order in ws ----------------
__global__ void pack_kernel(const float* __restrict__ Wq, const float* __restrict__ Wk,
                            const float* __restrict__ coef, const float* __restrict__ V,
                            const float* __restrict__ Uz, const float* __restrict__ Wz,
                            const float* __restrict__ Ur, const float* __restrict__ Wrg,
                            const float* __restrict__ Uh, const float* __restrict__ Wh,
                            unsigned short* __restrict__ ws) {
    int idx = blockIdx.x * 256 + threadIdx.x;   // grid covers exactly 43008
    if (idx < 24576) {                          // W6
        int mat = idx >> 12, rem = idx & 4095;
        int i = rem & 7, l = (rem >> 3) & 63, ks = (rem >> 9) & 1, nt = rem >> 10;
        int j = ks * 32 + ((l >> 4) << 3) + i, c = nt * 16 + (l & 15);
        const float* W = (mat == 0) ? Uz : (mat == 1) ? Wz : (mat == 2) ? Ur
                       : (mat == 3) ? Wrg : (mat == 4) ? Uh : Wh;
        ws[idx] = f2bf(W[j * 64 + c]);
    } else if (idx < 28672) {                   // WQK
        int rem = idx - 24576;
        int mq = rem >> 11; rem &= 2047;
        int i = rem & 7, l = (rem >> 3) & 63, nt = rem >> 9;
        int j = ((l >> 4) << 3) + i, c = nt * 16 + (l & 15);
        const float* W = mq ? Wk : Wq;
        ws[idx] = (j < M_) ? f2bf(W[j * 64 + c]) : (unsigned short)0;
    } else {                                    // WREL
        int rem = idx - 28672;
        int r = rem >> 11; rem &= 2047;
        int i = rem & 7, l = (rem >> 3) & 63, nt = rem >> 9;
        int j = ((l >> 4) << 3) + i, c = nt * 16 + (l & 15);
        unsigned short v = 0;
        if (j < M_) {
            float a = 0.f;
#pragma unroll
            for (int bb = 0; bb < 3; ++bb) a += coef[r * 3 + bb] * V[(bb * M_ + j) * 64 + c];
            v = f2bf(a);
        }
        ws[idx] = v;
    }
}

// --------- msg: one block per (t,b); msg bf16 -> upper half of out[t] rows ---------
__launch_bounds__(512, 4)
__global__ void msg_kernel(const float* __restrict__ x,
                           const float* __restrict__ As, const float* __restrict__ Af,
                           const float* __restrict__ At,
                           const unsigned short* __restrict__ wsF,
                           float* __restrict__ out) {
    __shared__ __align__(16) char smem[SMEM_A];
    const int blk = blockIdx.x;
    const int t = blk >> 8, b = blk & 255;
    const int tid = threadIdx.x, wv = tid >> 6, ln = tid & 63;
    const unsigned short* WQKF  = wsF + 24576;
    const unsigned short* WRELF = wsF + 28672;
    const float* __restrict__ xt = x + ((size_t)t * B_ + b) * (N_ * M_);

    // ---- p0: stage x A-frags + B-frags; zero S ----
    for (int e = tid; e < 1536; e += 512) {   // A-frags: row=n, k=feature m
        int mt = e >> 9, l = (e >> 3) & 63, i = e & 7;
        int row = mt * 16 + (l & 15), k = ((l >> 4) << 3) + i;
        float v = (row < N_ && k < M_) ? xt[row * M_ + k] : 0.f;
        *(unsigned short*)(smem + XA_OFF + e * 2) = f2bf(v);
    }
    for (int e = tid; e < 2048; e += 512) {   // B-frags: k=node index, c=feature
        int g = e >> 9, l = (e >> 3) & 63, i = e & 7;
        int ks = g >> 1, nt = g & 1;
        int k = ks * 32 + ((l >> 4) << 3) + i, c = nt * 16 + (l & 15);
        float v = (k < N_ && c < M_) ? xt[k * M_ + c] : 0.f;
        *(unsigned short*)(smem + XB_OFF + e * 2) = f2bf(v);
    }
    for (int e = tid; e < 35 * 36; e += 512) *(float*)(smem + S_OFF + e * 4) = 0.f;
    __syncthreads();

    // ---- p2: q = x@Wq (swz fp32), k = x@Wk (linear fp32) ----
    for (int tile = wv; tile < 24; tile += 8) {
        int qk = (tile >= 12) ? 1 : 0;
        int tt = tile - 12 * qk;
        int mt = tt >> 2, nt = tt & 3;
        short8 a  = *(const short8*)(smem + XA_OFF + (mt * 64 + ln) * 16);
        short8 bb = *(const short8*)(WQKF + (qk * 4 + nt) * 512 + ln * 8);
        f32x4 d = {0.f, 0.f, 0.f, 0.f};
        d = __builtin_amdgcn_mfma_f32_16x16x32_bf16(a, bb, d, 0, 0, 0);
        int col = nt * 16 + (ln & 15);
#pragma unroll
        for (int j = 0; j < 4; ++j) {
            int row = mt * 16 + ((ln >> 4) << 2) + j;
            if (row < N_) {
                if (qk) *(float*)(smem + K_OFF + (row * 64 + col) * 4) = d[j];
                else {
                    int ad = (Q_OFF + row * 256 + col * 4) ^ ((row & 7) << 4);
                    *(float*)(smem + ad) = d[j];
                }
            }
        }
    }
    __syncthreads();

    // ---- p3: wave = head; lane = n-row; atomicAdd softmax into S ----
    {
        const int hd = wv, n = ln, nn = (n < N_) ? n : 34;
        const int qb = Q_OFF + nn * 256 + hd * 32;
        const int swzq = (nn & 7) << 4;
        f32x4 q0 = *(const f32x4*)(smem + (qb ^ swzq));
        f32x4 q1 = *(const f32x4*)(smem + ((qb + 16) ^ swzq));
        float s[35];
#pragma unroll
        for (int m = 0; m < N_; ++m) {
            f32x4 k0 = *(const f32x4*)(smem + K_OFF + (m * 64 + hd * 8) * 4);
            f32x4 k1 = *(const f32x4*)(smem + K_OFF + (m * 64 + hd * 8 + 4) * 4);
            float acc = q0[0]*k0[0] + q0[1]*k0[1] + q0[2]*k0[2] + q0[3]*k0[3]
                      + q1[0]*k1[0] + q1[1]*k1[1] + q1[2]*k1[2] + q1[3]*k1[3];
            s[m] = acc * 0.3535533905932738f;
        }
        float mx = s[0];
#pragma unroll
        for (int m = 1; m < N_; ++m) mx = fmaxf(mx, s[m]);
        float sum = 0.f;
#pragma unroll
        for (int m = 0; m < N_; ++m) { s[m] = __expf(s[m] - mx); sum += s[m]; }
        float inv = 1.f / sum;
        if (n < N_) {
            float* Sp = (float*)(smem + S_OFF) + n * 36;
#pragma unroll
            for (int m = 0; m < N_; ++m) atomicAdd(Sp + m, s[m] * inv);
        }
    }
    __syncthreads();

    // ---- p4: An = l2norm(A * S) along n -> bf16 [3][35][40]; zero pad cols ----
    if (tid < 420) {
        int g = tid >> 2, sub = tid & 3;
        int mat = g / N_, j = g - N_ * mat;
        const float* __restrict__ A = (mat == 0) ? As : ((mat == 1) ? Af : At);
        float vals[9]; float ss = 0.f;
#pragma unroll
        for (int i = 0; i < 9; ++i) {
            int n = sub + 4 * i;
            float vv = 0.f;
            if (n < N_) vv = A[n * N_ + j] * *((const float*)(smem + S_OFF) + n * 36 + j);
            vals[i] = vv; ss += vv * vv;
        }
        ss += __shfl_xor(ss, 1);
        ss += __shfl_xor(ss, 2);
        float inv = 1.f / fmaxf(sqrtf(ss), 1e-12f);
#pragma unroll
        for (int i = 0; i < 9; ++i) {
            int n = sub + 4 * i;
            if (n < N_)
                *(unsigned short*)(smem + AN_OFF + ((mat * 35 + n) * 40 + j) * 2) = f2bf(vals[i] * inv);
        }
    }
    for (int e = tid; e < 525; e += 512) {    // pad cols 35..39 of each An row
        int mat = e / 175, rem = e - mat * 175;
        int n = rem / 5, pc = rem - n * 5;
        *(unsigned short*)(smem + AN_OFF + ((mat * 35 + n) * 40 + 35 + pc) * 2) = 0;
    }
    __syncthreads();

    // ---- p5a: 3 BASE products axb_i = An_i @ x (fp32 into LDS) ----
    for (int g = wv; g < 9; g += 8) {
        int base = g / 3, mt = g - 3 * base;
        const int row = mt * 16 + (ln & 15);
        const int rowc = (row < N_) ? row : 34;
        const short8 z8 = {0, 0, 0, 0, 0, 0, 0, 0};
        short8 aF[2];
#pragma unroll
        for (int ks = 0; ks < 2; ++ks) {
            int k0 = ks * 32 + ((ln >> 4) << 3);
            int k0c = (k0 <= 32) ? k0 : 32;
            short8 v = *(const short8*)(smem + AN_OFF + ((base * 35 + rowc) * 40 + k0c) * 2);
            aF[ks] = (row < N_ && k0 <= 32) ? v : z8;
        }
        float* axb = (float*)(smem + AXB_OFF) + base * (35 * 44);
#pragma unroll
        for (int nt = 0; nt < 2; ++nt) {
            f32x4 d = {0.f, 0.f, 0.f, 0.f};
#pragma unroll
            for (int ks = 0; ks < 2; ++ks) {
                short8 bb = *(const short8*)(smem + XB_OFF + ((ks * 2 + nt) * 64 + ln) * 16);
                d = __builtin_amdgcn_mfma_f32_16x16x32_bf16(aF[ks], bb, d, 0, 0, 0);
            }
            int col = nt * 16 + (ln & 15);
#pragma unroll
            for (int j = 0; j < 4; ++j) {
                int rw = mt * 16 + ((ln >> 4) << 2) + j;
                if (rw < N_) axb[rw * 44 + col] = d[j];
            }
        }
    }
    __syncthreads();

    // ---- p5c: per (r,mt): combine bases in regs -> A-frag -> MFMA @ Wrel -> bf16 out ----
    for (int g = wv; g < 21; g += 8) {
        int r = g / 3, mt = g - 3 * r;
        float c0, c1, c2;
        switch (r) {
            case 0: c0 = 1.f;  c1 = 0.f;  c2 = 0.f;  break;
            case 1: c0 = 0.f;  c1 = 1.f;  c2 = 0.f;  break;
            case 2: c0 = 0.f;  c1 = 0.f;  c2 = 1.f;  break;
            case 3: c0 = .5f;  c1 = .5f;  c2 = 0.f;  break;
            case 4: c0 = .5f;  c1 = 0.f;  c2 = .5f;  break;
            case 5: c0 = 0.f;  c1 = .5f;  c2 = .5f;  break;
            default: c0 = c1 = c2 = (1.f / 3.f);     break;
        }
        int row = mt * 16 + (ln & 15);
        float rvf = (row < N_) ? 1.f : 0.f;
        int rowc = (row < N_) ? row : 34;
        int k0 = (ln >> 4) << 3;
        const float* a0 = (const float*)(smem + AXB_OFF) + rowc * 44 + k0;
        const float* a1 = a0 + 35 * 44;
        const float* a2 = a1 + 35 * 44;
        f32x4 p0 = *(const f32x4*)a0,  p1 = *(const f32x4*)(a0 + 4);
        f32x4 u0 = *(const f32x4*)a1,  u1 = *(const f32x4*)(a1 + 4);
        f32x4 w0 = *(const f32x4*)a2,  w1 = *(const f32x4*)(a2 + 4);
        short8 aF;
#pragma unroll
        for (int i = 0; i < 4; ++i) {
            aF[i]     = (short)f2bf((c0 * p0[i] + c1 * u0[i] + c2 * w0[i]) * rvf);
            aF[i + 4] = (short)f2bf((c0 * p1[i] + c1 * u1[i] + c2 * w1[i]) * rvf);
        }
        unsigned short* outr = (unsigned short*)out
                             + (((size_t)t * R_ + r) * B_ + b) * ((size_t)N_ * 128);
#pragma unroll
        for (int nt = 0; nt < 4; ++nt) {
            short8 bb = *(const short8*)(WRELF + (r * 4 + nt) * 512 + ln * 8);
            f32x4 d = {0.f, 0.f, 0.f, 0.f};
            d = __builtin_amdgcn_mfma_f32_16x16x32_bf16(aF, bb, d, 0, 0, 0);
            int col = nt * 16 + (ln & 15);
#pragma unroll
            for (int j = 0; j < 4; ++j) {
                int rw = mt * 16 + ((ln >> 4) << 2) + j;
                if (rw < N_) outr[rw * 128 + 64 + col] = f2bf(fmaxf(d[j], 0.f));
            }
        }
    }
}

// ---- gate_kernel dynamic LDS: W6 copy + per-wave bounce ----
#define GATE_BOUNCE_STRIDE 66
#define GATE_LDS (49152 + 16 * 16 * GATE_BOUNCE_STRIDE * 2)   // 82944

__launch_bounds__(1024, 1)
__global__ void gate_kernel(const float* __restrict__ h0,
                            const unsigned short* __restrict__ wsF,
                            const float* __restrict__ bz, const float* __restrict__ brg,
                            const float* __restrict__ bh,
                            float* out) {
    extern __shared__ char gsm[];
    unsigned short* W6L = (unsigned short*)gsm;
    const int tid = threadIdx.x;
    const int wv = tid >> 6, ln = tid & 63;
    const int b = blockIdx.x;
    const int tile = wv;
    unsigned short* tb = (unsigned short*)(gsm + 49152) + wv * (16 * GATE_BOUNCE_STRIDE);
    const size_t TS = (size_t)R_ * B_ * N_ * 64;       // floats per t-slab

    for (int e = tid; e < 3072; e += 1024)
        ((short8*)W6L)[e] = ((const short8*)wsF)[e];
    __syncthreads();

    int ga = tile * 16 + (ln & 15); if (ga > 244) ga = 244;
    const size_t g_row = (size_t)((ga / 35) * B_ + b) * N_ + (ga % 35);
    const size_t aoff = g_row * 64 + ((ln >> 4) << 3);              // fp32 (h0)
    const size_t moff = g_row * 128 + 64 + ((ln >> 4) << 3);        // bf16 msg (shorts)
    const int colb = ln & 15;
    int coff[4]; bool vj[4];
#pragma unroll
    for (int j = 0; j < 4; ++j) {
        int g = tile * 16 + ((ln >> 4) << 2) + j;
        vj[j] = (g < 245);
        int gc = vj[j] ? g : 244;
        coff[j] = (((gc / 35) * B_ + b) * N_ + (gc % 35)) * 64;
    }
    float bzv[4], brv[4], bhv[4];
#pragma unroll
    for (int nt = 0; nt < 4; ++nt) {
        int c = nt * 16 + colb;
        bzv[nt] = bz[c]; brv[nt] = brg[c]; bhv[nt] = bh[c];
    }

    short8 ah[2];
    float hp[4][4];
    {
        const float* hA = h0 + aoff;
#pragma unroll
        for (int ks = 0; ks < 2; ++ks) {
            f32x4 u = *(const f32x4*)(hA + ks * 32);
            f32x4 v = *(const f32x4*)(hA + ks * 32 + 4);
            short8 s;
#pragma unroll
            for (int e = 0; e < 4; ++e) { s[e] = (short)f2bf(u[e]); s[e + 4] = (short)f2bf(v[e]); }
            ah[ks] = s;
        }
#pragma unroll
        for (int nt = 0; nt < 4; ++nt)
#pragma unroll
            for (int j = 0; j < 4; ++j) hp[nt][j] = h0[coff[j] + nt * 16 + colb];
    }
    // prefetch bf16 msg for t=0
    const unsigned short* outS = (const unsigned short*)out;
    short8 mpA = *(const short8*)(outS + moff);
    short8 mpB = *(const short8*)(outS + moff + 32);

    for (int t = 0; t < T_; ++t) {
        short8 amsg[2];
        amsg[0] = mpA; amsg[1] = mpB;
        {   // prefetch next t's msg (disjoint t-slab; clamped at end)
            int tn = (t < T_ - 1) ? (t + 1) : (T_ - 1);
            const unsigned short* mS = outS + (size_t)tn * (TS * 2) + moff;
            mpA = *(const short8*)(mS);
            mpB = *(const short8*)(mS + 32);
        }
        float zC[4][4];
#pragma unroll
        for (int nt = 0; nt < 4; ++nt) {
            f32x4 z  = {bzv[nt], bzv[nt], bzv[nt], bzv[nt]};
            f32x4 rg = {brv[nt], brv[nt], brv[nt], brv[nt]};
#pragma unroll
            for (int ks = 0; ks < 2; ++ks) {
                const unsigned short* wb = W6L + ln * 8 + nt * 1024 + ks * 512;
                z  = __builtin_amdgcn_mfma_f32_16x16x32_bf16(amsg[ks], *(const short8*)(wb),         z, 0, 0, 0);
                z  = __builtin_amdgcn_mfma_f32_16x16x32_bf16(ah[ks],   *(const short8*)(wb + 4096),  z, 0, 0, 0);
                rg = __builtin_amdgcn_mfma_f32_16x16x32_bf16(amsg[ks], *(const short8*)(wb + 8192),  rg, 0, 0, 0);
                rg = __builtin_amdgcn_mfma_f32_16x16x32_bf16(ah[ks],   *(const short8*)(wb + 12288), rg, 0, 0, 0);
            }
#pragma unroll
            for (int j = 0; j < 4; ++j) {
                float zv = 1.f / (1.f + __expf(-z[j]));
                float rv = 1.f / (1.f + __expf(-rg[j]));
                zC[nt][j] = zv;
                tb[(((ln >> 4) << 2) + j) * GATE_BOUNCE_STRIDE + nt * 16 + colb] = f2bf(rv * hp[nt][j]);
            }
        }
        short8 arh[2];
#pragma unroll
        for (int ks = 0; ks < 2; ++ks)
            arh[ks] = *(const short8*)(tb + (ln & 15) * GATE_BOUNCE_STRIDE + ks * 32 + ((ln >> 4) << 3));
        float* outT = out + (size_t)t * TS;
#pragma unroll
        for (int nt = 0; nt < 4; ++nt) {
            f32x4 m = {bhv[nt], bhv[nt], bhv[nt], bhv[nt]};
#pragma unroll
            for (int ks = 0; ks < 2; ++ks) {
                const unsigned short* wb = W6L + ln * 8 + nt * 1024 + ks * 512;
                m = __builtin_amdgcn_mfma_f32_16x16x32_bf16(amsg[ks], *(const short8*)(wb + 16384), m, 0, 0, 0);
                m = __builtin_amdgcn_mfma_f32_16x16x32_bf16(arh[ks],  *(const short8*)(wb + 20480), m, 0, 0, 0);
            }
#pragma unroll
            for (int j = 0; j < 4; ++j) {
                float e2 = __expf(2.f * m[j]);
                float th = 1.f - 2.f / (1.f + e2);
                float hn = hp[nt][j] + zC[nt][j] * (th - hp[nt][j]);
                hp[nt][j] = hn;
                if (vj[j]) outT[coff[j] + nt * 16 + colb] = hn;
                tb[(((ln >> 4) << 2) + j) * GATE_BOUNCE_STRIDE + nt * 16 + colb] = f2bf(hn);
            }
        }
#pragma unroll
        for (int ks = 0; ks < 2; ++ks)
            ah[ks] = *(const short8*)(tb + (ln & 15) * GATE_BOUNCE_STRIDE + ks * 32 + ((ln >> 4) << 3));
    }
}

extern "C" void kernel_launch(void* const* d_in, const int* in_sizes, int n_in,
                              void* d_out, int out_size, void* d_ws, size_t ws_size,
                              hipStream_t stream) {
    const float* x    = (const float*)d_in[0];
    const float* As   = (const float*)d_in[1];
    const float* Af   = (const float*)d_in[2];
    const float* At   = (const float*)d_in[3];
    const float* h0   = (const float*)d_in[4];
    const float* Wq   = (const float*)d_in[5];
    const float* Wk   = (const float*)d_in[6];
    const float* V    = (const float*)d_in[7];
    const float* coef = (const float*)d_in[8];
    const float* Uz   = (const float*)d_in[9];
    const float* Wz   = (const float*)d_in[10];
    const float* bz   = (const float*)d_in[11];
    const float* Ur   = (const float*)d_in[12];
    const float* Wrg  = (const float*)d_in[13];
    const float* brg  = (const float*)d_in[14];
    const float* Uh   = (const float*)d_in[15];
    const float* Wh   = (const float*)d_in[16];
    const float* bh   = (const float*)d_in[17];
    float* out = (float*)d_out;
    unsigned short* wsF = (unsigned short*)d_ws;  // 86016 B used

    hipFuncSetAttribute((const void*)gate_kernel,
                        hipFuncAttributeMaxDynamicSharedMemorySize, GATE_LDS);

    hipLaunchKernelGGL(pack_kernel, dim3(168), dim3(256), 0, stream,
                       Wq, Wk, coef, V, Uz, Wz, Ur, Wrg, Uh, Wh, wsF);
    hipLaunchKernelGGL(msg_kernel, dim3(T_ * B_), dim3(512), 0, stream,
                       x, As, Af, At, wsF, out);
    hipLaunchKernelGGL(gate_kernel, dim3(B_), dim3(1024), GATE_LDS, stream,
                       h0, wsF, bz, brg, bh, out);
}

// Round 8
// 188.536 us; speedup vs baseline: 4.3458x; 1.6569x over previous
//
#include <hip/hip_runtime.h>

typedef short short8 __attribute__((ext_vector_type(8)));
typedef float f32x4 __attribute__((ext_vector_type(4)));

#define T_ 12
#define B_ 256
#define N_ 35
#define M_ 29
#define H_ 64
#define R_ 7

// ---- ws (shorts) layout: packed bf16 MFMA B-fragments ----
// W6F   @0     : 6 mats x [nt4][ks2][64 lanes][8]  = 24576 shorts
// WQKF  @24576 : 2 mats x [nt4][64][8]             = 4096
// WRELF @28672 : 7 r    x [nt4][64][8]             = 14336

// ---- msg_kernel static LDS (bytes), phase-overlaid ----
#define XA_OFF   0        // x A-frags: 3 mt x [64][8] bf16          (3072)   p0..p5a
#define XB_OFF   3072     // x B-frags: [ks2][nt2][64][8] bf16       (4096)   p0..p5a
#define Q_OFF    7168     // fp32 [35][64] swz                       (9216)   p2..p3
#define K_OFF    16384    // fp32 [35][64] linear                    (8960)   p2..p3
#define E_OFF    25344    // bf16 exp(scores) [8][35][37]            (20720)  p3..p3.5
#define INV_OFF  46064    // fp32 inv rowsum [8][35]                 (1120)   p3..p3.5
#define S2_OFF   7168     // fp32 S [35][36] (over Q)                (5040)   p3.5..p4
#define AN_OFF   12208    // bf16 An [3][35][40] (over Q/K)          (8400)   p4..p5a
#define AXB_OFF  20608    // fp32 base products [3][35][44]          (18480)  p5a..p5c
#define SMEM_A   47232

__device__ __forceinline__ unsigned short f2bf(float f) {
    unsigned int u = __float_as_uint(f);
    u += 0x7fffu + ((u >> 16) & 1u);
    return (unsigned short)(u >> 16);
}
__device__ __forceinline__ float bf2f(unsigned short s) {
    return __uint_as_float(((unsigned int)s) << 16);
}

// ---------------- pack: weights -> bf16 fragment order in ws ----------------
__global__ void pack_kernel(const float* __restrict__ Wq, const float* __restrict__ Wk,
                            const float* __restrict__ coef, const float* __restrict__ V,
                            const float* __restrict__ Uz, const float* __restrict__ Wz,
                            const float* __restrict__ Ur, const float* __restrict__ Wrg,
                            const float* __restrict__ Uh, const float* __restrict__ Wh,
                            unsigned short* __restrict__ ws) {
    int idx = blockIdx.x * 256 + threadIdx.x;   // grid covers exactly 43008
    if (idx < 24576) {                          // W6
        int mat = idx >> 12, rem = idx & 4095;
        int i = rem & 7, l = (rem >> 3) & 63, ks = (rem >> 9) & 1, nt = rem >> 10;
        int j = ks * 32 + ((l >> 4) << 3) + i, c = nt * 16 + (l & 15);
        const float* W = (mat == 0) ? Uz : (mat == 1) ? Wz : (mat == 2) ? Ur
                       : (mat == 3) ? Wrg : (mat == 4) ? Uh : Wh;
        ws[idx] = f2bf(W[j * 64 + c]);
    } else if (idx < 28672) {                   // WQK
        int rem = idx - 24576;
        int mq = rem >> 11; rem &= 2047;
        int i = rem & 7, l = (rem >> 3) & 63, nt = rem >> 9;
        int j = ((l >> 4) << 3) + i, c = nt * 16 + (l & 15);
        const float* W = mq ? Wk : Wq;
        ws[idx] = (j < M_) ? f2bf(W[j * 64 + c]) : (unsigned short)0;
    } else {                                    // WREL
        int rem = idx - 28672;
        int r = rem >> 11; rem &= 2047;
        int i = rem & 7, l = (rem >> 3) & 63, nt = rem >> 9;
        int j = ((l >> 4) << 3) + i, c = nt * 16 + (l & 15);
        unsigned short v = 0;
        if (j < M_) {
            float a = 0.f;
#pragma unroll
            for (int bb = 0; bb < 3; ++bb) a += coef[r * 3 + bb] * V[(bb * M_ + j) * 64 + c];
            v = f2bf(a);
        }
        ws[idx] = v;
    }
}

// --------- msg: one block per (t,b); msg bf16 -> upper half of out[t] rows ---------
__launch_bounds__(512, 4)
__global__ void msg_kernel(const float* __restrict__ x,
                           const float* __restrict__ As, const float* __restrict__ Af,
                           const float* __restrict__ At,
                           const unsigned short* __restrict__ wsF,
                           float* __restrict__ out) {
    __shared__ __align__(16) char smem[SMEM_A];
    const int blk = blockIdx.x;
    const int t = blk >> 8, b = blk & 255;
    const int tid = threadIdx.x, wv = tid >> 6, ln = tid & 63;
    const unsigned short* WQKF  = wsF + 24576;
    const unsigned short* WRELF = wsF + 28672;
    const float* __restrict__ xt = x + ((size_t)t * B_ + b) * (N_ * M_);

    // ---- p0: stage x A-frags + B-frags ----
    for (int e = tid; e < 1536; e += 512) {   // A-frags: row=n, k=feature m
        int mt = e >> 9, l = (e >> 3) & 63, i = e & 7;
        int row = mt * 16 + (l & 15), k = ((l >> 4) << 3) + i;
        float v = (row < N_ && k < M_) ? xt[row * M_ + k] : 0.f;
        *(unsigned short*)(smem + XA_OFF + e * 2) = f2bf(v);
    }
    for (int e = tid; e < 2048; e += 512) {   // B-frags: k=node index, c=feature
        int g = e >> 9, l = (e >> 3) & 63, i = e & 7;
        int ks = g >> 1, nt = g & 1;
        int k = ks * 32 + ((l >> 4) << 3) + i, c = nt * 16 + (l & 15);
        float v = (k < N_ && c < M_) ? xt[k * M_ + c] : 0.f;
        *(unsigned short*)(smem + XB_OFF + e * 2) = f2bf(v);
    }
    __syncthreads();

    // ---- p2: q = x@Wq (swz fp32), k = x@Wk (linear fp32) ----
    for (int tile = wv; tile < 24; tile += 8) {
        int qk = (tile >= 12) ? 1 : 0;
        int tt = tile - 12 * qk;
        int mt = tt >> 2, nt = tt & 3;
        short8 a  = *(const short8*)(smem + XA_OFF + (mt * 64 + ln) * 16);
        short8 bb = *(const short8*)(WQKF + (qk * 4 + nt) * 512 + ln * 8);
        f32x4 d = {0.f, 0.f, 0.f, 0.f};
        d = __builtin_amdgcn_mfma_f32_16x16x32_bf16(a, bb, d, 0, 0, 0);
        int col = nt * 16 + (ln & 15);
#pragma unroll
        for (int j = 0; j < 4; ++j) {
            int row = mt * 16 + ((ln >> 4) << 2) + j;
            if (row < N_) {
                if (qk) *(float*)(smem + K_OFF + (row * 64 + col) * 4) = d[j];
                else {
                    int ad = (Q_OFF + row * 256 + col * 4) ^ ((row & 7) << 4);
                    *(float*)(smem + ad) = d[j];
                }
            }
        }
    }
    __syncthreads();

    // ---- p3: wave = head; lane = n-row; single-pass exp (no max, no atomics) ----
    {
        const int hd = wv, n = ln;
        const int nn = (n < N_) ? n : 34;
        const int qb = Q_OFF + nn * 256 + hd * 32;
        const int swzq = (nn & 7) << 4;
        f32x4 q0 = *(const f32x4*)(smem + (qb ^ swzq));
        f32x4 q1 = *(const f32x4*)(smem + ((qb + 16) ^ swzq));
        float sum = 0.f;
        unsigned short* Erow = (unsigned short*)(smem + E_OFF) + (hd * 35 + nn) * 37;
#pragma unroll
        for (int m = 0; m < N_; ++m) {
            f32x4 k0 = *(const f32x4*)(smem + K_OFF + (m * 64 + hd * 8) * 4);
            f32x4 k1 = *(const f32x4*)(smem + K_OFF + (m * 64 + hd * 8 + 4) * 4);
            float acc = q0[0]*k0[0] + q0[1]*k0[1] + q0[2]*k0[2] + q0[3]*k0[3]
                      + q1[0]*k1[0] + q1[1]*k1[1] + q1[2]*k1[2] + q1[3]*k1[3];
            float e = __expf(acc * 0.3535533905932738f);
            sum += e;
            if (n < N_) Erow[m] = f2bf(e);
        }
        if (n < N_) *((float*)(smem + INV_OFF) + hd * 35 + n) = 1.f / sum;
    }
    __syncthreads();

    // ---- p3.5: S[n][m] = sum_h E[h][n][m] * inv[h][n] ----
    {
        const unsigned short* E = (const unsigned short*)(smem + E_OFF);
        const float* IV = (const float*)(smem + INV_OFF);
        float* S = (float*)(smem + S2_OFF);
        for (int e = tid; e < 1225; e += 512) {
            int n = e / 35, m = e - n * 35;
            float s = 0.f;
#pragma unroll
            for (int h = 0; h < 8; ++h)
                s += bf2f(E[(h * 35 + n) * 37 + m]) * IV[h * 35 + n];
            S[n * 36 + m] = s;
        }
    }
    __syncthreads();

    // ---- p4: An = l2norm(A * S) along n -> bf16 [3][35][40]; zero pad cols ----
    if (tid < 420) {
        int g = tid >> 2, sub = tid & 3;
        int mat = g / N_, j = g - N_ * mat;
        const float* __restrict__ A = (mat == 0) ? As : ((mat == 1) ? Af : At);
        float vals[9]; float ss = 0.f;
#pragma unroll
        for (int i = 0; i < 9; ++i) {
            int n = sub + 4 * i;
            float vv = 0.f;
            if (n < N_) vv = A[n * N_ + j] * *((const float*)(smem + S2_OFF) + n * 36 + j);
            vals[i] = vv; ss += vv * vv;
        }
        ss += __shfl_xor(ss, 1);
        ss += __shfl_xor(ss, 2);
        float inv = 1.f / fmaxf(sqrtf(ss), 1e-12f);
#pragma unroll
        for (int i = 0; i < 9; ++i) {
            int n = sub + 4 * i;
            if (n < N_)
                *(unsigned short*)(smem + AN_OFF + ((mat * 35 + n) * 40 + j) * 2) = f2bf(vals[i] * inv);
        }
    }
    for (int e = tid; e < 525; e += 512) {    // pad cols 35..39 of each An row
        int mat = e / 175, rem = e - mat * 175;
        int n = rem / 5, pc = rem - n * 5;
        *(unsigned short*)(smem + AN_OFF + ((mat * 35 + n) * 40 + 35 + pc) * 2) = 0;
    }
    __syncthreads();

    // ---- p5a: 3 BASE products axb_i = An_i @ x (fp32 into LDS) ----
    for (int g = wv; g < 9; g += 8) {
        int base = g / 3, mt = g - 3 * base;
        const int row = mt * 16 + (ln & 15);
        const int rowc = (row < N_) ? row : 34;
        const short8 z8 = {0, 0, 0, 0, 0, 0, 0, 0};
        short8 aF[2];
#pragma unroll
        for (int ks = 0; ks < 2; ++ks) {
            int k0 = ks * 32 + ((ln >> 4) << 3);
            int k0c = (k0 <= 32) ? k0 : 32;
            short8 v = *(const short8*)(smem + AN_OFF + ((base * 35 + rowc) * 40 + k0c) * 2);
            aF[ks] = (row < N_ && k0 <= 32) ? v : z8;
        }
        float* axb = (float*)(smem + AXB_OFF) + base * (35 * 44);
#pragma unroll
        for (int nt = 0; nt < 2; ++nt) {
            f32x4 d = {0.f, 0.f, 0.f, 0.f};
#pragma unroll
            for (int ks = 0; ks < 2; ++ks) {
                short8 bb = *(const short8*)(smem + XB_OFF + ((ks * 2 + nt) * 64 + ln) * 16);
                d = __builtin_amdgcn_mfma_f32_16x16x32_bf16(aF[ks], bb, d, 0, 0, 0);
            }
            int col = nt * 16 + (ln & 15);
#pragma unroll
            for (int j = 0; j < 4; ++j) {
                int rw = mt * 16 + ((ln >> 4) << 2) + j;
                if (rw < N_) axb[rw * 44 + col] = d[j];
            }
        }
    }
    __syncthreads();

    // ---- p5c: per (r,mt): combine bases in regs -> A-frag -> MFMA @ Wrel -> bf16 out ----
    for (int g = wv; g < 21; g += 8) {
        int r = g / 3, mt = g - 3 * r;
        float c0, c1, c2;
        switch (r) {
            case 0: c0 = 1.f;  c1 = 0.f;  c2 = 0.f;  break;
            case 1: c0 = 0.f;  c1 = 1.f;  c2 = 0.f;  break;
            case 2: c0 = 0.f;  c1 = 0.f;  c2 = 1.f;  break;
            case 3: c0 = .5f;  c1 = .5f;  c2 = 0.f;  break;
            case 4: c0 = .5f;  c1 = 0.f;  c2 = .5f;  break;
            case 5: c0 = 0.f;  c1 = .5f;  c2 = .5f;  break;
            default: c0 = c1 = c2 = (1.f / 3.f);     break;
        }
        int row = mt * 16 + (ln & 15);
        float rvf = (row < N_) ? 1.f : 0.f;
        int rowc = (row < N_) ? row : 34;
        int k0 = (ln >> 4) << 3;
        const float* a0 = (const float*)(smem + AXB_OFF) + rowc * 44 + k0;
        const float* a1 = a0 + 35 * 44;
        const float* a2 = a1 + 35 * 44;
        f32x4 p0 = *(const f32x4*)a0,  p1 = *(const f32x4*)(a0 + 4);
        f32x4 u0 = *(const f32x4*)a1,  u1 = *(const f32x4*)(a1 + 4);
        f32x4 w0 = *(const f32x4*)a2,  w1 = *(const f32x4*)(a2 + 4);
        short8 aF;
#pragma unroll
        for (int i = 0; i < 4; ++i) {
            aF[i]     = (short)f2bf((c0 * p0[i] + c1 * u0[i] + c2 * w0[i]) * rvf);
            aF[i + 4] = (short)f2bf((c0 * p1[i] + c1 * u1[i] + c2 * w1[i]) * rvf);
        }
        unsigned short* outr = (unsigned short*)out
                             + (((size_t)t * R_ + r) * B_ + b) * ((size_t)N_ * 128);
#pragma unroll
        for (int nt = 0; nt < 4; ++nt) {
            short8 bb = *(const short8*)(WRELF + (r * 4 + nt) * 512 + ln * 8);
            f32x4 d = {0.f, 0.f, 0.f, 0.f};
            d = __builtin_amdgcn_mfma_f32_16x16x32_bf16(aF, bb, d, 0, 0, 0);
            int col = nt * 16 + (ln & 15);
#pragma unroll
            for (int j = 0; j < 4; ++j) {
                int rw = mt * 16 + ((ln >> 4) << 2) + j;
                if (rw < N_) outr[rw * 128 + 64 + col] = f2bf(fmaxf(d[j], 0.f));
            }
        }
    }
}

// ---- gate_kernel dynamic LDS: W6 copy + per-wave bounce ----
#define GATE_BOUNCE_STRIDE 66
#define GATE_LDS (49152 + 16 * 16 * GATE_BOUNCE_STRIDE * 2)   // 82944

__launch_bounds__(1024, 1)
__global__ void gate_kernel(const float* __restrict__ h0,
                            const unsigned short* __restrict__ wsF,
                            const float* __restrict__ bz, const float* __restrict__ brg,
                            const float* __restrict__ bh,
                            float* out) {
    extern __shared__ char gsm[];
    unsigned short* W6L = (unsigned short*)gsm;
    const int tid = threadIdx.x;
    const int wv = tid >> 6, ln = tid & 63;
    const int b = blockIdx.x;
    const int tile = wv;
    unsigned short* tb = (unsigned short*)(gsm + 49152) + wv * (16 * GATE_BOUNCE_STRIDE);
    const size_t TS = (size_t)R_ * B_ * N_ * 64;       // floats per t-slab

    for (int e = tid; e < 3072; e += 1024)
        ((short8*)W6L)[e] = ((const short8*)wsF)[e];
    __syncthreads();

    int ga = tile * 16 + (ln & 15); if (ga > 244) ga = 244;
    const size_t g_row = (size_t)((ga / 35) * B_ + b) * N_ + (ga % 35);
    const size_t aoff = g_row * 64 + ((ln >> 4) << 3);              // fp32 (h0)
    const size_t moff = g_row * 128 + 64 + ((ln >> 4) << 3);        // bf16 msg (shorts)
    const int colb = ln & 15;
    int coff[4]; bool vj[4];
#pragma unroll
    for (int j = 0; j < 4; ++j) {
        int g = tile * 16 + ((ln >> 4) << 2) + j;
        vj[j] = (g < 245);
        int gc = vj[j] ? g : 244;
        coff[j] = (((gc / 35) * B_ + b) * N_ + (gc % 35)) * 64;
    }
    float bzv[4], brv[4], bhv[4];
#pragma unroll
    for (int nt = 0; nt < 4; ++nt) {
        int c = nt * 16 + colb;
        bzv[nt] = bz[c]; brv[nt] = brg[c]; bhv[nt] = bh[c];
    }

    short8 ah[2];
    float hp[4][4];
    {
        const float* hA = h0 + aoff;
#pragma unroll
        for (int ks = 0; ks < 2; ++ks) {
            f32x4 u = *(const f32x4*)(hA + ks * 32);
            f32x4 v = *(const f32x4*)(hA + ks * 32 + 4);
            short8 s;
#pragma unroll
            for (int e = 0; e < 4; ++e) { s[e] = (short)f2bf(u[e]); s[e + 4] = (short)f2bf(v[e]); }
            ah[ks] = s;
        }
#pragma unroll
        for (int nt = 0; nt < 4; ++nt)
#pragma unroll
            for (int j = 0; j < 4; ++j) hp[nt][j] = h0[coff[j] + nt * 16 + colb];
    }
    // prefetch bf16 msg for t=0
    const unsigned short* outS = (const unsigned short*)out;
    short8 mpA = *(const short8*)(outS + moff);
    short8 mpB = *(const short8*)(outS + moff + 32);

    for (int t = 0; t < T_; ++t) {
        short8 amsg[2];
        amsg[0] = mpA; amsg[1] = mpB;
        {   // prefetch next t's msg (disjoint t-slab; clamped at end)
            int tn = (t < T_ - 1) ? (t + 1) : (T_ - 1);
            const unsigned short* mS = outS + (size_t)tn * (TS * 2) + moff;
            mpA = *(const short8*)(mS);
            mpB = *(const short8*)(mS + 32);
        }
        float zC[4][4];
#pragma unroll
        for (int nt = 0; nt < 4; ++nt) {
            f32x4 z  = {bzv[nt], bzv[nt], bzv[nt], bzv[nt]};
            f32x4 rg = {brv[nt], brv[nt], brv[nt], brv[nt]};
#pragma unroll
            for (int ks = 0; ks < 2; ++ks) {
                const unsigned short* wb = W6L + ln * 8 + nt * 1024 + ks * 512;
                z  = __builtin_amdgcn_mfma_f32_16x16x32_bf16(amsg[ks], *(const short8*)(wb),         z, 0, 0, 0);
                z  = __builtin_amdgcn_mfma_f32_16x16x32_bf16(ah[ks],   *(const short8*)(wb + 4096),  z, 0, 0, 0);
                rg = __builtin_amdgcn_mfma_f32_16x16x32_bf16(amsg[ks], *(const short8*)(wb + 8192),  rg, 0, 0, 0);
                rg = __builtin_amdgcn_mfma_f32_16x16x32_bf16(ah[ks],   *(const short8*)(wb + 12288), rg, 0, 0, 0);
            }
#pragma unroll
            for (int j = 0; j < 4; ++j) {
                float zv = 1.f / (1.f + __expf(-z[j]));
                float rv = 1.f / (1.f + __expf(-rg[j]));
                zC[nt][j] = zv;
                tb[(((ln >> 4) << 2) + j) * GATE_BOUNCE_STRIDE + nt * 16 + colb] = f2bf(rv * hp[nt][j]);
            }
        }
        short8 arh[2];
#pragma unroll
        for (int ks = 0; ks < 2; ++ks)
            arh[ks] = *(const short8*)(tb + (ln & 15) * GATE_BOUNCE_STRIDE + ks * 32 + ((ln >> 4) << 3));
        float* outT = out + (size_t)t * TS;
#pragma unroll
        for (int nt = 0; nt < 4; ++nt) {
            f32x4 m = {bhv[nt], bhv[nt], bhv[nt], bhv[nt]};
#pragma unroll
            for (int ks = 0; ks < 2; ++ks) {
                const unsigned short* wb = W6L + ln * 8 + nt * 1024 + ks * 512;
                m = __builtin_amdgcn_mfma_f32_16x16x32_bf16(amsg[ks], *(const short8*)(wb + 16384), m, 0, 0, 0);
                m = __builtin_amdgcn_mfma_f32_16x16x32_bf16(arh[ks],  *(const short8*)(wb + 20480), m, 0, 0, 0);
            }
#pragma unroll
            for (int j = 0; j < 4; ++j) {
                float e2 = __expf(2.f * m[j]);
                float th = 1.f - 2.f / (1.f + e2);
                float hn = hp[nt][j] + zC[nt][j] * (th - hp[nt][j]);
                hp[nt][j] = hn;
                if (vj[j]) outT[coff[j] + nt * 16 + colb] = hn;
                tb[(((ln >> 4) << 2) + j) * GATE_BOUNCE_STRIDE + nt * 16 + colb] = f2bf(hn);
            }
        }
#pragma unroll
        for (int ks = 0; ks < 2; ++ks)
            ah[ks] = *(const short8*)(tb + (ln & 15) * GATE_BOUNCE_STRIDE + ks * 32 + ((ln >> 4) << 3));
    }
}

extern "C" void kernel_launch(void* const* d_in, const int* in_sizes, int n_in,
                              void* d_out, int out_size, void* d_ws, size_t ws_size,
                              hipStream_t stream) {
    const float* x    = (const float*)d_in[0];
    const float* As   = (const float*)d_in[1];
    const float* Af   = (const float*)d_in[2];
    const float* At   = (const float*)d_in[3];
    const float* h0   = (const float*)d_in[4];
    const float* Wq   = (const float*)d_in[5];
    const float* Wk   = (const float*)d_in[6];
    const float* V    = (const float*)d_in[7];
    const float* coef = (const float*)d_in[8];
    const float* Uz   = (const float*)d_in[9];
    const float* Wz   = (const float*)d_in[10];
    const float* bz   = (const float*)d_in[11];
    const float* Ur   = (const float*)d_in[12];
    const float* Wrg  = (const float*)d_in[13];
    const float* brg  = (const float*)d_in[14];
    const float* Uh   = (const float*)d_in[15];
    const float* Wh   = (const float*)d_in[16];
    const float* bh   = (const float*)d_in[17];
    float* out = (float*)d_out;
    unsigned short* wsF = (unsigned short*)d_ws;  // 86016 B used

    hipFuncSetAttribute((const void*)gate_kernel,
                        hipFuncAttributeMaxDynamicSharedMemorySize, GATE_LDS);

    hipLaunchKernelGGL(pack_kernel, dim3(168), dim3(256), 0, stream,
                       Wq, Wk, coef, V, Uz, Wz, Ur, Wrg, Uh, Wh, wsF);
    hipLaunchKernelGGL(msg_kernel, dim3(T_ * B_), dim3(512), 0, stream,
                       x, As, Af, At, wsF, out);
    hipLaunchKernelGGL(gate_kernel, dim3(B_), dim3(1024), GATE_LDS, stream,
                       h0, wsF, bz, brg, bh, out);
}